// Round 7
// baseline (1505.400 us; speedup 1.0000x reference)
//
#include <hip/hip_runtime.h>
#include <hip/hip_bf16.h>

// Problem constants
// B=512, N(L)=256, D=128, DI=256, NL=4, NS=16, KC=4, DH=64, H=64
// M = B*N = 131072 tokens

typedef __bf16 bf16_8 __attribute__((ext_vector_type(8)));
typedef __bf16 bf16_4 __attribute__((ext_vector_type(4)));
typedef float  f32_4  __attribute__((ext_vector_type(4)));

// global_load_lds width-16: linear LDS dest (wave base + lane*16), per-lane
// pre-swizzled global source; reads apply the same XOR (both-sides swizzle).
#define GLOAD16(src, dst) __builtin_amdgcn_global_load_lds( \
    (const __attribute__((address_space(1))) void*)(src),   \
    (__attribute__((address_space(3))) void*)(dst), 16, 0, 0)

// fast sigmoid: native v_exp + v_rcp (bf16 output hides <=2ulp error)
__device__ __forceinline__ float fsig(float z) {
    float e = __expf(-z);
    return __builtin_amdgcn_rcpf(1.0f + e);
}

// ---------------------------------------------------------------------------
// prep: convert W_in (4*512*128), W_out (4*128*256), imp_W1 (64*128) fp32->bf16
__global__ __launch_bounds__(256) void prep_kernel(const float* __restrict__ win,
                                                   const float* __restrict__ wout,
                                                   const float* __restrict__ w1,
                                                   __bf16* __restrict__ win16,
                                                   __bf16* __restrict__ wout16,
                                                   __bf16* __restrict__ w116) {
    int i = blockIdx.x * 256 + threadIdx.x;
    if (i < 4 * 512 * 128) win16[i] = (__bf16)win[i];
    if (i < 4 * 128 * 256) wout16[i] = (__bf16)wout[i];
    if (i < 64 * 128)      w116[i]  = (__bf16)w1[i];
}

// ---------------------------------------------------------------------------
// build_T: T[layer][l][j] = Kk[l-j] + (l==j)*Dp, 0 for j>l  (bf16, 256x256/layer)
// Also emits row sums Rg[layer][l] = sum_j T[l,j] (of the bf16-rounded values).
__global__ __launch_bounds__(256) void build_T_kernel(const float* __restrict__ Bp,
                                                      const float* __restrict__ Cp,
                                                      const float* __restrict__ ldt,
                                                      const float* __restrict__ Dpv,
                                                      __bf16* __restrict__ Tg,
                                                      float* __restrict__ Rg) {
    __shared__ float rsum[4];
    int layer = blockIdx.y, l = blockIdx.x, j = threadIdx.x;
    int d = l - j;
    float val = 0.0f;
    if (d >= 0) {
        float dt = expf(ldt[layer]);
        dt = fminf(fmaxf(dt, 1e-4f), 1.0f);
        #pragma unroll
        for (int n = 0; n < 16; ++n) {
            float A = -(float)(n + 1);
            float e = fminf(fmaxf(dt * A, -10.0f), 10.0f);
            float dA = expf(e);
            float dB = (dA - 1.0f) / A * Bp[layer * 16 + n];
            val += Cp[layer * 16 + n] * dB * expf(e * (float)d);
        }
        if (d == 0) val += Dpv[layer];
    }
    __bf16 bv = (__bf16)val;
    Tg[layer * 65536 + l * 256 + j] = bv;
    float fv = (float)bv;
    #pragma unroll
    for (int o = 32; o; o >>= 1) fv += __shfl_xor(fv, o);
    int lane = j & 63, wave = j >> 6;
    if (lane == 0) rsum[wave] = fv;
    __syncthreads();
    if (j == 0) Rg[layer * 256 + l] = rsum[0] + rsum[1] + rsum[2] + rsum[3];
}

// ---------------------------------------------------------------------------
// Fused add_pos + first LayerNorm, float4-vectorized: 32 lanes per token.
// x = init+pos (fp32, residual), h = LN(x) bf16.
__global__ __launch_bounds__(256) void ln_first_kernel(const float4* __restrict__ init4,
                                                       const float4* __restrict__ pos4,
                                                       const float* __restrict__ g,
                                                       const float* __restrict__ bta,
                                                       float4* __restrict__ x4,
                                                       __bf16* __restrict__ h) {
    int tid = threadIdx.x;
    int wave = tid >> 6, lane = tid & 63;
    int half = lane >> 5, l32 = lane & 31;
    long tok = (long)blockIdx.x * 8 + wave * 2 + half;
    float4 v = init4[tok * 32 + l32];
    float4 p = pos4[(tok & 255) * 32 + l32];
    v.x += p.x; v.y += p.y; v.z += p.z; v.w += p.w;
    x4[tok * 32 + l32] = v;
    float s = v.x + v.y + v.z + v.w;
    float ss = v.x * v.x + v.y * v.y + v.z * v.z + v.w * v.w;
    #pragma unroll
    for (int o = 16; o; o >>= 1) { s += __shfl_xor(s, o); ss += __shfl_xor(ss, o); }
    float m = s * (1.0f / 128.0f);
    float var = ss * (1.0f / 128.0f) - m * m;
    float r = rsqrtf(var + 1e-5f);
    bf16_4 hv;
    int d0 = l32 * 4;
    hv[0] = (__bf16)((v.x - m) * r * g[d0]     + bta[d0]);
    hv[1] = (__bf16)((v.y - m) * r * g[d0 + 1] + bta[d0 + 1]);
    hv[2] = (__bf16)((v.z - m) * r * g[d0 + 2] + bta[d0 + 2]);
    hv[3] = (__bf16)((v.w - m) * r * g[d0 + 3] + bta[d0 + 3]);
    *(bf16_4*)(h + tok * 128 + d0) = hv;
}

// ---------------------------------------------------------------------------
// GEMM1: xz[m,n] = sum_k h[m,k] * Win[n,k]; M=131072, N=512, K=128.
// Staging via global_load_lds (linear LDS, source-XOR swizzle).
// 1D grid 4096, XCD-aware fold: the 4 n-tiles of one m-tile share bid%8
// (same XCD) and dispatch within a 32-bid window -> h tile is L2-hit 3 of 4x.
// xp written TRANSPOSED (RAW, pre-conv): xpt[b][n][l]; z written in [m][c].
__global__ __launch_bounds__(256) void gemm1_kernel(const __bf16* __restrict__ hmat,
                                                    const __bf16* __restrict__ win,
                                                    __bf16* __restrict__ xpt,
                                                    __bf16* __restrict__ z) {
    __shared__ __align__(16) __bf16 As[128 * 64];   // 16 KB
    __shared__ __align__(16) __bf16 Bs[128 * 64];   // 16 KB
    int tid = threadIdx.x;
    int bid = blockIdx.x;
    // decode: m = (bid&7) + 8*(bid>>5), n = (bid>>3)&3  (bijective, 4096 blocks)
    long m0 = (long)((bid & 7) + ((bid >> 5) << 3)) * 128;
    int n0 = ((bid >> 3) & 3) * 128;
    int wave = tid >> 6, lane = tid & 63;
    int wm = wave >> 1, wn = wave & 1;
    int lrow = lane & 15, lk = (lane >> 4) * 8;
    int r7 = lrow & 7;
    int rl = lane >> 3, sl = lane & 7;
    int scol = ((sl ^ rl) << 3);                    // source-swizzled 16B chunk
    f32_4 acc[4][4] = {};

    for (int kc = 0; kc < 2; ++kc) {
        const __bf16* asrc = hmat + m0 * 128 + kc * 64;
        const __bf16* bsrc = win + (long)n0 * 128 + kc * 64;
        #pragma unroll
        for (int j = 0; j < 4; ++j) {               // A: 16 chunks of 8 rows
            int chunk = wave * 4 + j;
            GLOAD16(asrc + (long)(chunk * 8 + rl) * 128 + scol, As + chunk * 512);
            GLOAD16(bsrc + (long)(chunk * 8 + rl) * 128 + scol, Bs + chunk * 512);
        }
        __syncthreads();
        #pragma unroll
        for (int kk = 0; kk < 64; kk += 32) {
            int sw = ((((kk + lk) >> 3) ^ r7) << 3);
            bf16_8 a[4], b[4];
            #pragma unroll
            for (int mt = 0; mt < 4; ++mt)
                a[mt] = *(const bf16_8*)(As + (wm * 64 + mt * 16 + lrow) * 64 + sw);
            #pragma unroll
            for (int nt = 0; nt < 4; ++nt)
                b[nt] = *(const bf16_8*)(Bs + (wn * 64 + nt * 16 + lrow) * 64 + sw);
            #pragma unroll
            for (int mt = 0; mt < 4; ++mt)
                #pragma unroll
                for (int nt = 0; nt < 4; ++nt)
                    acc[mt][nt] = __builtin_amdgcn_mfma_f32_16x16x32_bf16(
                        a[mt], b[nt], acc[mt][nt], 0, 0, 0);
        }
        __syncthreads();
    }

    int row_base = (lane >> 4) * 4;
    int col = lane & 15;
    if (n0 < 256) {
        // xp branch: transposed packed write xpt[b][n][l..l+3]
        #pragma unroll
        for (int mt = 0; mt < 4; ++mt) {
            long mg = m0 + wm * 64 + mt * 16 + row_base;
            int b = (int)(mg >> 8), l = (int)(mg & 255);  // l multiple of 4 -> 8B aligned
            #pragma unroll
            for (int nt = 0; nt < 4; ++nt) {
                int ng = n0 + wn * 64 + nt * 16 + col;
                bf16_4 o;
                #pragma unroll
                for (int r = 0; r < 4; ++r) o[r] = (__bf16)acc[mt][nt][r];
                *(bf16_4*)(xpt + (long)b * 65536 + (long)ng * 256 + l) = o;
            }
        }
    } else {
        int ncol0 = n0 - 256;
        #pragma unroll
        for (int mt = 0; mt < 4; ++mt) {
            long mg = m0 + wm * 64 + mt * 16 + row_base;
            #pragma unroll
            for (int nt = 0; nt < 4; ++nt) {
                int ng = ncol0 + wn * 64 + nt * 16 + col;
                #pragma unroll
                for (int r = 0; r < 4; ++r)
                    z[(mg + r) * 256 + ng] = (__bf16)acc[mt][nt][r];
            }
        }
    }
}

// ---------------------------------------------------------------------------
// SSM: P = T @ xp (per-batch Toeplitz GEMM, global_load_lds staging), conv(K=4)
// applied to P in the EPILOGUE via shifted-P identity; y *= sigmoid(z) in place.
// One block per (batch, channel-half): BM=256, BN=128, 512 threads.
// launch_bounds (512,6): target 3 blocks/CU (LDS 51.7KB x3 fits in 160KB).
__global__ __launch_bounds__(512, 6) void ssm_gemm_kernel(const __bf16* __restrict__ xct,
                                                          __bf16* __restrict__ zy,
                                                          const __bf16* __restrict__ Tg,
                                                          const float* __restrict__ Rg,
                                                          const float* __restrict__ cw,
                                                          const float* __restrict__ cb) {
    __shared__ __align__(16) __bf16 As[256 * 64];   // 32 KB (T rows, K-chunk)
    __shared__ __align__(16) __bf16 Bs[128 * 64];   // 16 KB (x channels, K-chunk)
    __shared__ float  bnd[3][128];      // P rows 125..127 for wm=0 -> wm=1 handoff
    __shared__ float  Rs[256];
    int tid = threadIdx.x;
    int batch = blockIdx.x >> 1;
    int ntile = blockIdx.x & 1;
    int c0 = ntile * 128;

    int wave = tid >> 6, lane = tid & 63;
    int wm = wave >> 2, wn = wave & 3;          // 2 x 4 wave grid
    int lrow = lane & 15, lk = (lane >> 4) * 8;
    int r7 = lrow & 7;
    int quad = lane >> 4;
    int rl = lane >> 3, sl = lane & 7;
    int scol = ((sl ^ rl) << 3);
    f32_4 acc[8][2] = {};
    const __bf16* bsrc0 = xct + (long)batch * 65536 + (long)c0 * 256;

    if (tid < 256) Rs[tid] = Rg[tid];

    for (int kc = 0; kc < 4; ++kc) {
        int j0 = kc * 64;
        const __bf16* asrc = Tg + j0;
        const __bf16* bsrc = bsrc0 + j0;
        #pragma unroll
        for (int j = 0; j < 4; ++j) {           // A: 32 chunks / 8 waves
            int chunk = wave * 4 + j;
            GLOAD16(asrc + (long)(chunk * 8 + rl) * 256 + scol, As + chunk * 512);
        }
        #pragma unroll
        for (int j = 0; j < 2; ++j) {           // B: 16 chunks / 8 waves
            int chunk = wave * 2 + j;
            GLOAD16(bsrc + (long)(chunk * 8 + rl) * 256 + scol, Bs + chunk * 512);
        }
        __syncthreads();
        #pragma unroll
        for (int kk = 0; kk < 64; kk += 32) {
            int sw = ((((kk + lk) >> 3) ^ r7) << 3);
            bf16_8 b0 = *(const bf16_8*)(Bs + (wn * 32 + lrow) * 64 + sw);
            bf16_8 b1 = *(const bf16_8*)(Bs + (wn * 32 + 16 + lrow) * 64 + sw);
            #pragma unroll
            for (int mt = 0; mt < 8; ++mt) {
                bf16_8 a = *(const bf16_8*)(As + (wm * 128 + mt * 16 + lrow) * 64 + sw);
                acc[mt][0] = __builtin_amdgcn_mfma_f32_16x16x32_bf16(a, b0, acc[mt][0], 0, 0, 0);
                acc[mt][1] = __builtin_amdgcn_mfma_f32_16x16x32_bf16(a, b1, acc[mt][1], 0, 0, 0);
            }
        }
        __syncthreads();
    }

    // publish P rows 125..127 (wm=0, top tile, quad 3, r=1..3) for wm=1 waves
    if (wm == 0 && quad == 3) {
        #pragma unroll
        for (int nt = 0; nt < 2; ++nt) {
            int colb = wn * 32 + nt * 16 + lrow;
            bnd[0][colb] = acc[7][nt][1];   // P[125]
            bnd[1][colb] = acc[7][nt][2];   // P[126]
            bnd[2][colb] = acc[7][nt][3];   // P[127]
        }
    }
    __syncthreads();

    // per-channel conv weights
    float4 wv[2]; float cbv[2];
    #pragma unroll
    for (int nt = 0; nt < 2; ++nt) {
        int cg = c0 + wn * 32 + nt * 16 + lrow;
        wv[nt] = *(const float4*)(cw + cg * 4);
        cbv[nt] = cb[cg];
    }
    int src = (lane + 48) & 63;   // quad>0: lane-16 ; quad==0: lane+48

    #pragma unroll
    for (int mt = 0; mt < 8; ++mt) {
        int lbase = wm * 128 + mt * 16 + quad * 4;
        int mp = mt > 0 ? mt - 1 : 0;
        float R0 = Rs[lbase], R1 = Rs[lbase + 1], R2 = Rs[lbase + 2], R3 = Rs[lbase + 3];
        #pragma unroll
        for (int nt = 0; nt < 2; ++nt) {
            int colb = wn * 32 + nt * 16 + lrow;
            int cg = c0 + colb;
            // P at rows lbase-1, lbase-2, lbase-3
            float s1 = __shfl(acc[mt][nt][3], src);
            float s2 = __shfl(acc[mt][nt][2], src);
            float s3 = __shfl(acc[mt][nt][1], src);
            float t1, t2, t3;
            if (mt == 0) {
                if (wm == 1) { t1 = bnd[2][colb]; t2 = bnd[1][colb]; t3 = bnd[0][colb]; }
                else         { t1 = 0.0f; t2 = 0.0f; t3 = 0.0f; }
            } else {
                t1 = __shfl(acc[mp][nt][3], src);
                t2 = __shfl(acc[mp][nt][2], src);
                t3 = __shfl(acc[mp][nt][1], src);
            }
            float pm1 = quad ? s1 : t1;
            float pm2 = quad ? s2 : t2;
            float pm3 = quad ? s3 : t3;
            float p0 = acc[mt][nt][0], p1 = acc[mt][nt][1];
            float p2 = acc[mt][nt][2], p3 = acc[mt][nt][3];
            float y0 = wv[nt].x * pm3 + wv[nt].y * pm2 + wv[nt].z * pm1 + wv[nt].w * p0 + cbv[nt] * R0;
            float y1 = wv[nt].x * pm2 + wv[nt].y * pm1 + wv[nt].z * p0  + wv[nt].w * p1 + cbv[nt] * R1;
            float y2 = wv[nt].x * pm1 + wv[nt].y * p0  + wv[nt].z * p1  + wv[nt].w * p2 + cbv[nt] * R2;
            float y3 = wv[nt].x * p0  + wv[nt].y * p1  + wv[nt].z * p2  + wv[nt].w * p3 + cbv[nt] * R3;
            long base = (long)batch * 65536 + (long)lbase * 256 + cg;
            float z0 = (float)zy[base];
            float z1 = (float)zy[base + 256];
            float z2 = (float)zy[base + 512];
            float z3 = (float)zy[base + 768];
            zy[base]       = (__bf16)(y0 * fsig(z0));
            zy[base + 256] = (__bf16)(y1 * fsig(z1));
            zy[base + 512] = (__bf16)(y2 * fsig(z2));
            zy[base + 768] = (__bf16)(y3 * fsig(z3));
        }
    }
}

// ---------------------------------------------------------------------------
// GEMM2 + residual + FUSED LayerNorm epilogue (global_load_lds staging).
//   xn[m,d] = x[m,d] + clip(rs)*sum_c y[m,c]*Wout[d,c]   (M=131072,N=128,K=256)
// M-tile 64 (grid 2048) for occupancy; block owns full 128-d rows -> LN local.
// final_mode==0: LN(xn) bf16 -> hout.  final_mode==1: LN(xn) fp32 -> tokens_out.
__global__ __launch_bounds__(256) void gemm2_kernel(const __bf16* __restrict__ y,
                                                    const __bf16* __restrict__ wout,
                                                    float* __restrict__ x,
                                                    const float* __restrict__ rs_p,
                                                    const float* __restrict__ g,
                                                    const float* __restrict__ bta,
                                                    __bf16* __restrict__ hout,
                                                    float* __restrict__ tokens_out,
                                                    int final_mode) {
    __shared__ __align__(16) __bf16 As[64 * 64];    // 8 KB
    __shared__ __align__(16) __bf16 Bs[128 * 64];   // 16 KB
    __shared__ float s_sum[64][2];
    __shared__ float s_ssq[64][2];
    int tid = threadIdx.x;
    long m0 = (long)blockIdx.x * 64;
    int wave = tid >> 6, lane = tid & 63;
    int wm = wave >> 1, wn = wave & 1;
    int lrow = lane & 15, lk = (lane >> 4) * 8;
    int r7 = lrow & 7;
    int rl = lane >> 3, sl = lane & 7;
    int scol = ((sl ^ rl) << 3);
    f32_4 acc[2][4] = {};

    for (int kc = 0; kc < 4; ++kc) {
        const __bf16* asrc = y + m0 * 256 + kc * 64;
        const __bf16* bsrc = wout + kc * 64;
        #pragma unroll
        for (int j = 0; j < 2; ++j) {               // A: 8 chunk-groups / 4 waves
            int chunk = wave * 2 + j;
            GLOAD16(asrc + (long)(chunk * 8 + rl) * 256 + scol, As + chunk * 512);
        }
        #pragma unroll
        for (int j = 0; j < 4; ++j) {               // B: 16 chunk-groups / 4 waves
            int chunk = wave * 4 + j;
            GLOAD16(bsrc + (long)(chunk * 8 + rl) * 256 + scol, Bs + chunk * 512);
        }
        __syncthreads();
        #pragma unroll
        for (int kk = 0; kk < 64; kk += 32) {
            int sw = ((((kk + lk) >> 3) ^ r7) << 3);
            bf16_8 a[2], b[4];
            #pragma unroll
            for (int mt = 0; mt < 2; ++mt)
                a[mt] = *(const bf16_8*)(As + (wm * 32 + mt * 16 + lrow) * 64 + sw);
            #pragma unroll
            for (int nt = 0; nt < 4; ++nt)
                b[nt] = *(const bf16_8*)(Bs + (wn * 64 + nt * 16 + lrow) * 64 + sw);
            #pragma unroll
            for (int mt = 0; mt < 2; ++mt)
                #pragma unroll
                for (int nt = 0; nt < 4; ++nt)
                    acc[mt][nt] = __builtin_amdgcn_mfma_f32_16x16x32_bf16(
                        a[mt], b[nt], acc[mt][nt], 0, 0, 0);
        }
        __syncthreads();
    }

    float rs = rs_p[0];
    rs = fminf(fmaxf(rs, 0.0f), 1.5f);
    int quad = lane >> 4;
    int col = lane & 15;

    // Phase A: xn = x + rs*acc (overwrite acc); per-token partial sum/sumsq
    #pragma unroll
    for (int mt = 0; mt < 2; ++mt) {
        int tb = wm * 32 + mt * 16 + quad * 4;
        long mg = m0 + tb;
        #pragma unroll
        for (int r = 0; r < 4; ++r) {
            float s = 0.0f, ss = 0.0f;
            #pragma unroll
            for (int nt = 0; nt < 4; ++nt) {
                int d = wn * 64 + nt * 16 + col;
                float xv = x[(mg + r) * 128 + d] + rs * acc[mt][nt][r];
                acc[mt][nt][r] = xv;
                s += xv; ss += xv * xv;
            }
            #pragma unroll
            for (int o = 8; o; o >>= 1) { s += __shfl_xor(s, o); ss += __shfl_xor(ss, o); }
            if (col == 0) {
                s_sum[tb + r][wn] = s;
                s_ssq[tb + r][wn] = ss;
            }
        }
    }
    __syncthreads();

    // Phase B: finish LN, write outputs
    #pragma unroll
    for (int mt = 0; mt < 2; ++mt) {
        int tb = wm * 32 + mt * 16 + quad * 4;
        long mg = m0 + tb;
        #pragma unroll
        for (int r = 0; r < 4; ++r) {
            float s  = s_sum[tb + r][0] + s_sum[tb + r][1];
            float ss = s_ssq[tb + r][0] + s_ssq[tb + r][1];
            float m = s * (1.0f / 128.0f);
            float var = ss * (1.0f / 128.0f) - m * m;
            float rstd = rsqrtf(var + 1e-5f);
            #pragma unroll
            for (int nt = 0; nt < 4; ++nt) {
                int d = wn * 64 + nt * 16 + col;
                float xv = acc[mt][nt][r];
                x[(mg + r) * 128 + d] = xv;
                float t = (xv - m) * rstd * g[d] + bta[d];
                if (!final_mode) {
                    hout[(mg + r) * 128 + d] = (__bf16)t;
                } else {
                    tokens_out[(mg + r) * 128 + d] = t;
                }
            }
        }
    }
}

// ---------------------------------------------------------------------------
// L2-normalize tokens rows -> tn (bf16).  float4-vectorized, 32 lanes/token.
__global__ __launch_bounds__(256) void l2n_kernel(const float4* __restrict__ tokens4,
                                                  __bf16* __restrict__ tn) {
    int tid = threadIdx.x;
    int wave = tid >> 6, lane = tid & 63;
    int half = lane >> 5, l32 = lane & 31;
    long tok = (long)blockIdx.x * 8 + wave * 2 + half;
    float4 t = tokens4[tok * 32 + l32];
    float q = t.x * t.x + t.y * t.y + t.z * t.z + t.w * t.w;
    #pragma unroll
    for (int o = 16; o; o >>= 1) q += __shfl_xor(q, o);
    float inv = 1.0f / fmaxf(sqrtf(q), 1e-6f);
    bf16_4 o4;
    o4[0] = (__bf16)(t.x * inv); o4[1] = (__bf16)(t.y * inv);
    o4[2] = (__bf16)(t.z * inv); o4[3] = (__bf16)(t.w * inv);
    *(bf16_4*)(tn + tok * 128 + l32 * 4) = o4;
}

// ---------------------------------------------------------------------------
// MLP via MFMA: logits[m] = gelu(tn[m,:] @ W1.T + b1) @ W2 + b2
#define LDA 136   // 128 + 8 pad (bf16 elems), row stride 272 B
__global__ __launch_bounds__(256) void mlp_kernel(const __bf16* __restrict__ tn,
                                                  const __bf16* __restrict__ w1b,
                                                  const float* __restrict__ b1,
                                                  const float* __restrict__ W2,
                                                  const float* __restrict__ b2,
                                                  float* __restrict__ logits) {
    __shared__ __bf16 As[128 * LDA];   // 34816 B
    __shared__ __bf16 Bs[64 * LDA];    // 17408 B
    int tid = threadIdx.x;
    long m0 = (long)blockIdx.x * 128;
    const __bf16* asrc = tn + m0 * 128;
    #pragma unroll
    for (int i = 0; i < 8; ++i) {
        int idx = tid + i * 256;           // 0..2047
        int row = idx >> 4, c = idx & 15;  // 16 uint4 per row
        uint4 v = *(const uint4*)(asrc + row * 128 + c * 8);
        *(uint4*)(As + row * LDA + c * 8) = v;
    }
    #pragma unroll
    for (int i = 0; i < 4; ++i) {
        int idx = tid + i * 256;
        int row = idx >> 4, c = idx & 15;
        uint4 v = *(const uint4*)(w1b + row * 128 + c * 8);
        *(uint4*)(Bs + row * LDA + c * 8) = v;
    }
    __syncthreads();

    int wave = tid >> 6, lane = tid & 63;
    int lrow = lane & 15, lk = (lane >> 4) * 8;
    f32_4 acc[2][4] = {};
    #pragma unroll
    for (int kk = 0; kk < 128; kk += 32) {
        bf16_8 a[2], b[4];
        #pragma unroll
        for (int mt = 0; mt < 2; ++mt)
            a[mt] = *(const bf16_8*)(As + (wave * 32 + mt * 16 + lrow) * LDA + kk + lk);
        #pragma unroll
        for (int nt = 0; nt < 4; ++nt)
            b[nt] = *(const bf16_8*)(Bs + (nt * 16 + lrow) * LDA + kk + lk);
        #pragma unroll
        for (int mt = 0; mt < 2; ++mt)
            #pragma unroll
            for (int nt = 0; nt < 4; ++nt)
                acc[mt][nt] = __builtin_amdgcn_mfma_f32_16x16x32_bf16(
                    a[mt], b[nt], acc[mt][nt], 0, 0, 0);
    }

    int col = lane & 15, quad = lane >> 4;
    float b2v = b2[0];
    #pragma unroll
    for (int mt = 0; mt < 2; ++mt) {
        #pragma unroll
        for (int r = 0; r < 4; ++r) {
            float p = 0.0f;
            #pragma unroll
            for (int nt = 0; nt < 4; ++nt) {
                int jx = nt * 16 + col;
                float a = acc[mt][nt][r] + b1[jx];
                float gl = 0.5f * a * (1.0f + erff(a * 0.70710678118654752f));
                p += gl * W2[jx];
            }
            #pragma unroll
            for (int o = 8; o; o >>= 1) p += __shfl_xor(p, o);
            if (col == 0) {
                long tok = m0 + wave * 32 + mt * 16 + quad * 4 + r;
                logits[tok] = p + b2v;
            }
        }
    }
}

// ---------------------------------------------------------------------------
// Per-batch softmax over L, feats = sum_l w_l * tokens, 3 small head linears
__global__ __launch_bounds__(256) void head_kernel(const float* __restrict__ tokens,
                                                   const float* __restrict__ logits,
                                                   const float* __restrict__ texW,
                                                   const float* __restrict__ texb,
                                                   const float* __restrict__ edgeW,
                                                   const float* __restrict__ edgeb,
                                                   const float* __restrict__ strW,
                                                   const float* __restrict__ strb,
                                                   float* __restrict__ feats_out,
                                                   float* __restrict__ tex_out,
                                                   float* __restrict__ edge_out,
                                                   float* __restrict__ str_out,
                                                   float* __restrict__ w_out) {
    __shared__ float wsm[256];
    __shared__ float red[8];
    __shared__ float feats_s[128];
    int b = blockIdx.x, tid = threadIdx.x;
    int lane = tid & 63, wave = tid >> 6;
    float lg = logits[(long)b * 256 + tid];
    float mx = lg;
    #pragma unroll
    for (int o = 32; o; o >>= 1) mx = fmaxf(mx, __shfl_xor(mx, o));
    if (lane == 0) red[wave] = mx;
    __syncthreads();
    float bm = fmaxf(fmaxf(red[0], red[1]), fmaxf(red[2], red[3]));
    float e = expf(lg - bm);
    float se = e;
    #pragma unroll
    for (int o = 32; o; o >>= 1) se += __shfl_xor(se, o);
    if (lane == 0) red[4 + wave] = se;
    __syncthreads();
    float tot = red[4] + red[5] + red[6] + red[7];
    float w = e / tot;
    wsm[tid] = w;
    w_out[(long)b * 256 + tid] = w;
    __syncthreads();
    if (tid < 128) {
        float acc = 0.0f;
        const float* tb = tokens + (long)b * 256 * 128 + tid;
        #pragma unroll 4
        for (int l = 0; l < 256; ++l) acc += tb[l * 128] * wsm[l];
        feats_s[tid] = acc;
        feats_out[(long)b * 128 + tid] = acc;
    }
    __syncthreads();
    if (tid < 192) {
        int head = tid >> 6, j = tid & 63;
        const float* W  = head == 0 ? texW : (head == 1 ? edgeW : strW);
        const float* bi = head == 0 ? texb : (head == 1 ? edgeb : strb);
        float* outp     = head == 0 ? tex_out : (head == 1 ? edge_out : str_out);
        const float* wr = W + j * 128;
        float acc = 0.0f;
        #pragma unroll 8
        for (int k = 0; k < 128; ++k) acc += feats_s[k] * wr[k];
        outp[(long)b * 64 + j] = acc + bi[j];
    }
}

// ---------------------------------------------------------------------------
extern "C" void kernel_launch(void* const* d_in, const int* in_sizes, int n_in,
                              void* d_out, int out_size, void* d_ws, size_t ws_size,
                              hipStream_t stream) {
    const float* init   = (const float*)d_in[0];
    const float* pos    = (const float*)d_in[1];
    const float* ln_g   = (const float*)d_in[2];
    const float* ln_b   = (const float*)d_in[3];
    const float* W_in   = (const float*)d_in[4];
    const float* conv_w = (const float*)d_in[5];
    const float* conv_b = (const float*)d_in[6];
    const float* ssm_B  = (const float*)d_in[7];
    const float* ssm_C  = (const float*)d_in[8];
    const float* log_dt = (const float*)d_in[9];
    const float* ssm_D  = (const float*)d_in[10];
    const float* W_out  = (const float*)d_in[11];
    const float* res_sc = (const float*)d_in[12];
    const float* fin_g  = (const float*)d_in[13];
    const float* fin_b  = (const float*)d_in[14];
    const float* imp_W1 = (const float*)d_in[15];
    const float* imp_b1 = (const float*)d_in[16];
    const float* imp_W2 = (const float*)d_in[17];
    const float* imp_b2 = (const float*)d_in[18];
    const float* tex_W  = (const float*)d_in[19];
    const float* tex_b  = (const float*)d_in[20];
    const float* edge_W = (const float*)d_in[21];
    const float* edge_b = (const float*)d_in[22];
    const float* str_W  = (const float*)d_in[23];
    const float* str_b  = (const float*)d_in[24];

    float* out = (float*)d_out;
    char* ws = (char*)d_ws;
    float*  x      = (float*)ws;                      // 67108864 B  (M*D fp32)
    __bf16* xpt    = (__bf16*)(ws + 67108864);        // 67108864 B  (xp transposed [b][c][l])
    __bf16* zb     = (__bf16*)(ws + 134217728);       // 67108864 B  (z; y in place)
    __bf16* hb     = (__bf16*)(ws + 201326592);       // 33554432 B  (M*D bf16; reused as tn)
    __bf16* win16  = (__bf16*)(ws + 234881024);       // 524288 B
    __bf16* wout16 = (__bf16*)(ws + 235405312);       // 262144 B
    float*  logits = (float*)(ws + 235667456);        // 524288 B
    __bf16* w1b    = (__bf16*)(ws + 236191744);       // 16384 B
    __bf16* Tg     = (__bf16*)(ws + 236208128);       // 524288 B (4 layers x 256x256 bf16)
    float*  Rg     = (float*)(ws + 236732416);        // 4096 B (4 layers x 256 row sums)

    float* tokens = out + 163840;

    prep_kernel<<<1024, 256, 0, stream>>>(W_in, W_out, imp_W1, win16, wout16, w1b);
    build_T_kernel<<<dim3(256, 4), 256, 0, stream>>>(ssm_B, ssm_C, log_dt, ssm_D, Tg, Rg);
    ln_first_kernel<<<16384, 256, 0, stream>>>((const float4*)init, (const float4*)pos,
                                               ln_g, ln_b, (float4*)x, hb);
    for (int l = 0; l < 4; ++l) {
        gemm1_kernel<<<4096, 256, 0, stream>>>(hb, win16 + l * 65536, xpt, zb);
        ssm_gemm_kernel<<<1024, 512, 0, stream>>>(xpt, zb, Tg + l * 65536, Rg + l * 256,
                                                  conv_w + l * 1024, conv_b + l * 256);
        int fin = (l == 3);
        const float* gn = fin ? fin_g : ln_g + (l + 1) * 128;
        const float* bn = fin ? fin_b : ln_b + (l + 1) * 128;
        gemm2_kernel<<<2048, 256, 0, stream>>>(zb, wout16 + l * 32768, x, res_sc + l,
                                               gn, bn, hb, fin ? tokens : nullptr, fin);
    }
    __bf16* tn = hb;  // hb is dead after the layer loop; l2n writes tn here
    l2n_kernel<<<16384, 256, 0, stream>>>((const float4*)tokens, tn);
    mlp_kernel<<<1024, 256, 0, stream>>>(tn, w1b, imp_b1, imp_W2, imp_b2, logits);
    head_kernel<<<512, 256, 0, stream>>>(tokens, logits, tex_W, tex_b, edge_W, edge_b,
                                         str_W, str_b, out, out + 65536, out + 98304,
                                         out + 131072, out + 16941056);
}

// Round 8
// 766.887 us; speedup vs baseline: 1.9630x; 1.9630x over previous
//
#include <hip/hip_runtime.h>
#include <hip/hip_bf16.h>

// Problem constants
// B=512, N(L)=256, D=128, DI=256, NL=4, NS=16, KC=4, DH=64, H=64
// M = B*N = 131072 tokens

typedef __bf16 bf16_8 __attribute__((ext_vector_type(8)));
typedef __bf16 bf16_4 __attribute__((ext_vector_type(4)));
typedef float  f32_4  __attribute__((ext_vector_type(4)));

// global_load_lds width-16: linear LDS dest (wave base + lane*16), per-lane
// pre-swizzled global source; reads apply the same XOR (both-sides swizzle).
#define GLOAD16(src, dst) __builtin_amdgcn_global_load_lds( \
    (const __attribute__((address_space(1))) void*)(src),   \
    (__attribute__((address_space(3))) void*)(dst), 16, 0, 0)

// fast sigmoid: native v_exp + v_rcp (bf16 output hides <=2ulp error)
__device__ __forceinline__ float fsig(float z) {
    float e = __expf(-z);
    return __builtin_amdgcn_rcpf(1.0f + e);
}

// ---------------------------------------------------------------------------
// prep: convert W_in (4*512*128), W_out (4*128*256), imp_W1 (64*128) fp32->bf16
__global__ __launch_bounds__(256) void prep_kernel(const float* __restrict__ win,
                                                   const float* __restrict__ wout,
                                                   const float* __restrict__ w1,
                                                   __bf16* __restrict__ win16,
                                                   __bf16* __restrict__ wout16,
                                                   __bf16* __restrict__ w116) {
    int i = blockIdx.x * 256 + threadIdx.x;
    if (i < 4 * 512 * 128) win16[i] = (__bf16)win[i];
    if (i < 4 * 128 * 256) wout16[i] = (__bf16)wout[i];
    if (i < 64 * 128)      w116[i]  = (__bf16)w1[i];
}

// ---------------------------------------------------------------------------
// build_T: T[layer][l][j] = Kk[l-j] + (l==j)*Dp, 0 for j>l  (bf16, 256x256/layer)
// Also emits row sums Rg[layer][l] = sum_j T[l,j] (of the bf16-rounded values).
__global__ __launch_bounds__(256) void build_T_kernel(const float* __restrict__ Bp,
                                                      const float* __restrict__ Cp,
                                                      const float* __restrict__ ldt,
                                                      const float* __restrict__ Dpv,
                                                      __bf16* __restrict__ Tg,
                                                      float* __restrict__ Rg) {
    __shared__ float rsum[4];
    int layer = blockIdx.y, l = blockIdx.x, j = threadIdx.x;
    int d = l - j;
    float val = 0.0f;
    if (d >= 0) {
        float dt = expf(ldt[layer]);
        dt = fminf(fmaxf(dt, 1e-4f), 1.0f);
        #pragma unroll
        for (int n = 0; n < 16; ++n) {
            float A = -(float)(n + 1);
            float e = fminf(fmaxf(dt * A, -10.0f), 10.0f);
            float dA = expf(e);
            float dB = (dA - 1.0f) / A * Bp[layer * 16 + n];
            val += Cp[layer * 16 + n] * dB * expf(e * (float)d);
        }
        if (d == 0) val += Dpv[layer];
    }
    __bf16 bv = (__bf16)val;
    Tg[layer * 65536 + l * 256 + j] = bv;
    float fv = (float)bv;
    #pragma unroll
    for (int o = 32; o; o >>= 1) fv += __shfl_xor(fv, o);
    int lane = j & 63, wave = j >> 6;
    if (lane == 0) rsum[wave] = fv;
    __syncthreads();
    if (j == 0) Rg[layer * 256 + l] = rsum[0] + rsum[1] + rsum[2] + rsum[3];
}

// ---------------------------------------------------------------------------
// Fused add_pos + first LayerNorm, float4-vectorized: 32 lanes per token.
// x = init+pos (fp32, residual), h = LN(x) bf16.
__global__ __launch_bounds__(256) void ln_first_kernel(const float4* __restrict__ init4,
                                                       const float4* __restrict__ pos4,
                                                       const float* __restrict__ g,
                                                       const float* __restrict__ bta,
                                                       float4* __restrict__ x4,
                                                       __bf16* __restrict__ h) {
    int tid = threadIdx.x;
    int wave = tid >> 6, lane = tid & 63;
    int half = lane >> 5, l32 = lane & 31;
    long tok = (long)blockIdx.x * 8 + wave * 2 + half;
    float4 v = init4[tok * 32 + l32];
    float4 p = pos4[(tok & 255) * 32 + l32];
    v.x += p.x; v.y += p.y; v.z += p.z; v.w += p.w;
    x4[tok * 32 + l32] = v;
    float s = v.x + v.y + v.z + v.w;
    float ss = v.x * v.x + v.y * v.y + v.z * v.z + v.w * v.w;
    #pragma unroll
    for (int o = 16; o; o >>= 1) { s += __shfl_xor(s, o); ss += __shfl_xor(ss, o); }
    float m = s * (1.0f / 128.0f);
    float var = ss * (1.0f / 128.0f) - m * m;
    float r = rsqrtf(var + 1e-5f);
    bf16_4 hv;
    int d0 = l32 * 4;
    hv[0] = (__bf16)((v.x - m) * r * g[d0]     + bta[d0]);
    hv[1] = (__bf16)((v.y - m) * r * g[d0 + 1] + bta[d0 + 1]);
    hv[2] = (__bf16)((v.z - m) * r * g[d0 + 2] + bta[d0 + 2]);
    hv[3] = (__bf16)((v.w - m) * r * g[d0 + 3] + bta[d0 + 3]);
    *(bf16_4*)(h + tok * 128 + d0) = hv;
}

// ---------------------------------------------------------------------------
// GEMM1: xz[m,n] = sum_k h[m,k] * Win[n,k]; M=131072, N=512, K=128.
// Staging via global_load_lds (linear LDS, source-XOR swizzle).
// 1D grid 4096, XCD-aware fold: the 4 n-tiles of one m-tile share bid%8
// (same XCD) and dispatch within a 32-bid window -> h tile is L2-hit 3 of 4x.
// xp written TRANSPOSED (RAW, pre-conv): xpt[b][n][l]; z written in [m][c].
__global__ __launch_bounds__(256) void gemm1_kernel(const __bf16* __restrict__ hmat,
                                                    const __bf16* __restrict__ win,
                                                    __bf16* __restrict__ xpt,
                                                    __bf16* __restrict__ z) {
    __shared__ __align__(16) __bf16 As[128 * 64];   // 16 KB
    __shared__ __align__(16) __bf16 Bs[128 * 64];   // 16 KB
    int tid = threadIdx.x;
    int bid = blockIdx.x;
    // decode: m = (bid&7) + 8*(bid>>5), n = (bid>>3)&3  (bijective, 4096 blocks)
    long m0 = (long)((bid & 7) + ((bid >> 5) << 3)) * 128;
    int n0 = ((bid >> 3) & 3) * 128;
    int wave = tid >> 6, lane = tid & 63;
    int wm = wave >> 1, wn = wave & 1;
    int lrow = lane & 15, lk = (lane >> 4) * 8;
    int r7 = lrow & 7;
    int rl = lane >> 3, sl = lane & 7;
    int scol = ((sl ^ rl) << 3);                    // source-swizzled 16B chunk
    f32_4 acc[4][4] = {};

    for (int kc = 0; kc < 2; ++kc) {
        const __bf16* asrc = hmat + m0 * 128 + kc * 64;
        const __bf16* bsrc = win + (long)n0 * 128 + kc * 64;
        #pragma unroll
        for (int j = 0; j < 4; ++j) {               // A: 16 chunks of 8 rows
            int chunk = wave * 4 + j;
            GLOAD16(asrc + (long)(chunk * 8 + rl) * 128 + scol, As + chunk * 512);
            GLOAD16(bsrc + (long)(chunk * 8 + rl) * 128 + scol, Bs + chunk * 512);
        }
        __syncthreads();
        #pragma unroll
        for (int kk = 0; kk < 64; kk += 32) {
            int sw = ((((kk + lk) >> 3) ^ r7) << 3);
            bf16_8 a[4], b[4];
            #pragma unroll
            for (int mt = 0; mt < 4; ++mt)
                a[mt] = *(const bf16_8*)(As + (wm * 64 + mt * 16 + lrow) * 64 + sw);
            #pragma unroll
            for (int nt = 0; nt < 4; ++nt)
                b[nt] = *(const bf16_8*)(Bs + (wn * 64 + nt * 16 + lrow) * 64 + sw);
            #pragma unroll
            for (int mt = 0; mt < 4; ++mt)
                #pragma unroll
                for (int nt = 0; nt < 4; ++nt)
                    acc[mt][nt] = __builtin_amdgcn_mfma_f32_16x16x32_bf16(
                        a[mt], b[nt], acc[mt][nt], 0, 0, 0);
        }
        __syncthreads();
    }

    int row_base = (lane >> 4) * 4;
    int col = lane & 15;
    if (n0 < 256) {
        // xp branch: transposed packed write xpt[b][n][l..l+3]
        #pragma unroll
        for (int mt = 0; mt < 4; ++mt) {
            long mg = m0 + wm * 64 + mt * 16 + row_base;
            int b = (int)(mg >> 8), l = (int)(mg & 255);  // l multiple of 4 -> 8B aligned
            #pragma unroll
            for (int nt = 0; nt < 4; ++nt) {
                int ng = n0 + wn * 64 + nt * 16 + col;
                bf16_4 o;
                #pragma unroll
                for (int r = 0; r < 4; ++r) o[r] = (__bf16)acc[mt][nt][r];
                *(bf16_4*)(xpt + (long)b * 65536 + (long)ng * 256 + l) = o;
            }
        }
    } else {
        int ncol0 = n0 - 256;
        #pragma unroll
        for (int mt = 0; mt < 4; ++mt) {
            long mg = m0 + wm * 64 + mt * 16 + row_base;
            #pragma unroll
            for (int nt = 0; nt < 4; ++nt) {
                int ng = ncol0 + wn * 64 + nt * 16 + col;
                #pragma unroll
                for (int r = 0; r < 4; ++r)
                    z[(mg + r) * 256 + ng] = (__bf16)acc[mt][nt][r];
            }
        }
    }
}

// ---------------------------------------------------------------------------
// SSM: P = T @ xp (per-batch Toeplitz GEMM, global_load_lds staging), conv(K=4)
// applied to P in the EPILOGUE via shifted-P identity; y *= sigmoid(z) in place.
// One block per (batch, channel-half): BM=256, BN=128, 512 threads.
// NOTE: plain launch_bounds(512) — (512,6) starved VGPRs (40, acc spilled to
// scratch: WRITE_SIZE 66->462MB, dur 63->236us).  Round-7 lesson.
__global__ __launch_bounds__(512) void ssm_gemm_kernel(const __bf16* __restrict__ xct,
                                                       __bf16* __restrict__ zy,
                                                       const __bf16* __restrict__ Tg,
                                                       const float* __restrict__ Rg,
                                                       const float* __restrict__ cw,
                                                       const float* __restrict__ cb) {
    __shared__ __align__(16) __bf16 As[256 * 64];   // 32 KB (T rows, K-chunk)
    __shared__ __align__(16) __bf16 Bs[128 * 64];   // 16 KB (x channels, K-chunk)
    __shared__ float  bnd[3][128];      // P rows 125..127 for wm=0 -> wm=1 handoff
    __shared__ float  Rs[256];
    int tid = threadIdx.x;
    int batch = blockIdx.x >> 1;
    int ntile = blockIdx.x & 1;
    int c0 = ntile * 128;

    int wave = tid >> 6, lane = tid & 63;
    int wm = wave >> 2, wn = wave & 3;          // 2 x 4 wave grid
    int lrow = lane & 15, lk = (lane >> 4) * 8;
    int r7 = lrow & 7;
    int quad = lane >> 4;
    int rl = lane >> 3, sl = lane & 7;
    int scol = ((sl ^ rl) << 3);
    f32_4 acc[8][2] = {};
    const __bf16* bsrc0 = xct + (long)batch * 65536 + (long)c0 * 256;

    if (tid < 256) Rs[tid] = Rg[tid];

    for (int kc = 0; kc < 4; ++kc) {
        int j0 = kc * 64;
        const __bf16* asrc = Tg + j0;
        const __bf16* bsrc = bsrc0 + j0;
        #pragma unroll
        for (int j = 0; j < 4; ++j) {           // A: 32 chunks / 8 waves
            int chunk = wave * 4 + j;
            GLOAD16(asrc + (long)(chunk * 8 + rl) * 256 + scol, As + chunk * 512);
        }
        #pragma unroll
        for (int j = 0; j < 2; ++j) {           // B: 16 chunks / 8 waves
            int chunk = wave * 2 + j;
            GLOAD16(bsrc + (long)(chunk * 8 + rl) * 256 + scol, Bs + chunk * 512);
        }
        __syncthreads();
        #pragma unroll
        for (int kk = 0; kk < 64; kk += 32) {
            int sw = ((((kk + lk) >> 3) ^ r7) << 3);
            bf16_8 b0 = *(const bf16_8*)(Bs + (wn * 32 + lrow) * 64 + sw);
            bf16_8 b1 = *(const bf16_8*)(Bs + (wn * 32 + 16 + lrow) * 64 + sw);
            #pragma unroll
            for (int mt = 0; mt < 8; ++mt) {
                bf16_8 a = *(const bf16_8*)(As + (wm * 128 + mt * 16 + lrow) * 64 + sw);
                acc[mt][0] = __builtin_amdgcn_mfma_f32_16x16x32_bf16(a, b0, acc[mt][0], 0, 0, 0);
                acc[mt][1] = __builtin_amdgcn_mfma_f32_16x16x32_bf16(a, b1, acc[mt][1], 0, 0, 0);
            }
        }
        __syncthreads();
    }

    // publish P rows 125..127 (wm=0, top tile, quad 3, r=1..3) for wm=1 waves
    if (wm == 0 && quad == 3) {
        #pragma unroll
        for (int nt = 0; nt < 2; ++nt) {
            int colb = wn * 32 + nt * 16 + lrow;
            bnd[0][colb] = acc[7][nt][1];   // P[125]
            bnd[1][colb] = acc[7][nt][2];   // P[126]
            bnd[2][colb] = acc[7][nt][3];   // P[127]
        }
    }
    __syncthreads();

    // per-channel conv weights
    float4 wv[2]; float cbv[2];
    #pragma unroll
    for (int nt = 0; nt < 2; ++nt) {
        int cg = c0 + wn * 32 + nt * 16 + lrow;
        wv[nt] = *(const float4*)(cw + cg * 4);
        cbv[nt] = cb[cg];
    }
    int src = (lane + 48) & 63;   // quad>0: lane-16 ; quad==0: lane+48

    #pragma unroll
    for (int mt = 0; mt < 8; ++mt) {
        int lbase = wm * 128 + mt * 16 + quad * 4;
        int mp = mt > 0 ? mt - 1 : 0;
        float R0 = Rs[lbase], R1 = Rs[lbase + 1], R2 = Rs[lbase + 2], R3 = Rs[lbase + 3];
        #pragma unroll
        for (int nt = 0; nt < 2; ++nt) {
            int colb = wn * 32 + nt * 16 + lrow;
            int cg = c0 + colb;
            // P at rows lbase-1, lbase-2, lbase-3
            float s1 = __shfl(acc[mt][nt][3], src);
            float s2 = __shfl(acc[mt][nt][2], src);
            float s3 = __shfl(acc[mt][nt][1], src);
            float t1, t2, t3;
            if (mt == 0) {
                if (wm == 1) { t1 = bnd[2][colb]; t2 = bnd[1][colb]; t3 = bnd[0][colb]; }
                else         { t1 = 0.0f; t2 = 0.0f; t3 = 0.0f; }
            } else {
                t1 = __shfl(acc[mp][nt][3], src);
                t2 = __shfl(acc[mp][nt][2], src);
                t3 = __shfl(acc[mp][nt][1], src);
            }
            float pm1 = quad ? s1 : t1;
            float pm2 = quad ? s2 : t2;
            float pm3 = quad ? s3 : t3;
            float p0 = acc[mt][nt][0], p1 = acc[mt][nt][1];
            float p2 = acc[mt][nt][2], p3 = acc[mt][nt][3];
            float y0 = wv[nt].x * pm3 + wv[nt].y * pm2 + wv[nt].z * pm1 + wv[nt].w * p0 + cbv[nt] * R0;
            float y1 = wv[nt].x * pm2 + wv[nt].y * pm1 + wv[nt].z * p0  + wv[nt].w * p1 + cbv[nt] * R1;
            float y2 = wv[nt].x * pm1 + wv[nt].y * p0  + wv[nt].z * p1  + wv[nt].w * p2 + cbv[nt] * R2;
            float y3 = wv[nt].x * p0  + wv[nt].y * p1  + wv[nt].z * p2  + wv[nt].w * p3 + cbv[nt] * R3;
            long base = (long)batch * 65536 + (long)lbase * 256 + cg;
            float z0 = (float)zy[base];
            float z1 = (float)zy[base + 256];
            float z2 = (float)zy[base + 512];
            float z3 = (float)zy[base + 768];
            zy[base]       = (__bf16)(y0 * fsig(z0));
            zy[base + 256] = (__bf16)(y1 * fsig(z1));
            zy[base + 512] = (__bf16)(y2 * fsig(z2));
            zy[base + 768] = (__bf16)(y3 * fsig(z3));
        }
    }
}

// ---------------------------------------------------------------------------
// GEMM2 + residual + FUSED LayerNorm epilogue (global_load_lds staging).
//   xn[m,d] = x[m,d] + clip(rs)*sum_c y[m,c]*Wout[d,c]   (M=131072,N=128,K=256)
// M-tile 64 (grid 2048) for occupancy; block owns full 128-d rows -> LN local.
// final_mode==0: LN(xn) bf16 -> hout.  final_mode==1: LN(xn) fp32 -> tokens_out.
__global__ __launch_bounds__(256) void gemm2_kernel(const __bf16* __restrict__ y,
                                                    const __bf16* __restrict__ wout,
                                                    float* __restrict__ x,
                                                    const float* __restrict__ rs_p,
                                                    const float* __restrict__ g,
                                                    const float* __restrict__ bta,
                                                    __bf16* __restrict__ hout,
                                                    float* __restrict__ tokens_out,
                                                    int final_mode) {
    __shared__ __align__(16) __bf16 As[64 * 64];    // 8 KB
    __shared__ __align__(16) __bf16 Bs[128 * 64];   // 16 KB
    __shared__ float s_sum[64][2];
    __shared__ float s_ssq[64][2];
    int tid = threadIdx.x;
    long m0 = (long)blockIdx.x * 64;
    int wave = tid >> 6, lane = tid & 63;
    int wm = wave >> 1, wn = wave & 1;
    int lrow = lane & 15, lk = (lane >> 4) * 8;
    int r7 = lrow & 7;
    int rl = lane >> 3, sl = lane & 7;
    int scol = ((sl ^ rl) << 3);
    f32_4 acc[2][4] = {};

    for (int kc = 0; kc < 4; ++kc) {
        const __bf16* asrc = y + m0 * 256 + kc * 64;
        const __bf16* bsrc = wout + kc * 64;
        #pragma unroll
        for (int j = 0; j < 2; ++j) {               // A: 8 chunk-groups / 4 waves
            int chunk = wave * 2 + j;
            GLOAD16(asrc + (long)(chunk * 8 + rl) * 256 + scol, As + chunk * 512);
        }
        #pragma unroll
        for (int j = 0; j < 4; ++j) {               // B: 16 chunk-groups / 4 waves
            int chunk = wave * 4 + j;
            GLOAD16(bsrc + (long)(chunk * 8 + rl) * 256 + scol, Bs + chunk * 512);
        }
        __syncthreads();
        #pragma unroll
        for (int kk = 0; kk < 64; kk += 32) {
            int sw = ((((kk + lk) >> 3) ^ r7) << 3);
            bf16_8 a[2], b[4];
            #pragma unroll
            for (int mt = 0; mt < 2; ++mt)
                a[mt] = *(const bf16_8*)(As + (wm * 32 + mt * 16 + lrow) * 64 + sw);
            #pragma unroll
            for (int nt = 0; nt < 4; ++nt)
                b[nt] = *(const bf16_8*)(Bs + (wn * 64 + nt * 16 + lrow) * 64 + sw);
            #pragma unroll
            for (int mt = 0; mt < 2; ++mt)
                #pragma unroll
                for (int nt = 0; nt < 4; ++nt)
                    acc[mt][nt] = __builtin_amdgcn_mfma_f32_16x16x32_bf16(
                        a[mt], b[nt], acc[mt][nt], 0, 0, 0);
        }
        __syncthreads();
    }

    float rs = rs_p[0];
    rs = fminf(fmaxf(rs, 0.0f), 1.5f);
    int quad = lane >> 4;
    int col = lane & 15;

    // Phase A: xn = x + rs*acc (overwrite acc); per-token partial sum/sumsq
    #pragma unroll
    for (int mt = 0; mt < 2; ++mt) {
        int tb = wm * 32 + mt * 16 + quad * 4;
        long mg = m0 + tb;
        #pragma unroll
        for (int r = 0; r < 4; ++r) {
            float s = 0.0f, ss = 0.0f;
            #pragma unroll
            for (int nt = 0; nt < 4; ++nt) {
                int d = wn * 64 + nt * 16 + col;
                float xv = x[(mg + r) * 128 + d] + rs * acc[mt][nt][r];
                acc[mt][nt][r] = xv;
                s += xv; ss += xv * xv;
            }
            #pragma unroll
            for (int o = 8; o; o >>= 1) { s += __shfl_xor(s, o); ss += __shfl_xor(ss, o); }
            if (col == 0) {
                s_sum[tb + r][wn] = s;
                s_ssq[tb + r][wn] = ss;
            }
        }
    }
    __syncthreads();

    // Phase B: finish LN, write outputs
    #pragma unroll
    for (int mt = 0; mt < 2; ++mt) {
        int tb = wm * 32 + mt * 16 + quad * 4;
        long mg = m0 + tb;
        #pragma unroll
        for (int r = 0; r < 4; ++r) {
            float s  = s_sum[tb + r][0] + s_sum[tb + r][1];
            float ss = s_ssq[tb + r][0] + s_ssq[tb + r][1];
            float m = s * (1.0f / 128.0f);
            float var = ss * (1.0f / 128.0f) - m * m;
            float rstd = rsqrtf(var + 1e-5f);
            #pragma unroll
            for (int nt = 0; nt < 4; ++nt) {
                int d = wn * 64 + nt * 16 + col;
                float xv = acc[mt][nt][r];
                x[(mg + r) * 128 + d] = xv;
                float t = (xv - m) * rstd * g[d] + bta[d];
                if (!final_mode) {
                    hout[(mg + r) * 128 + d] = (__bf16)t;
                } else {
                    tokens_out[(mg + r) * 128 + d] = t;
                }
            }
        }
    }
}

// ---------------------------------------------------------------------------
// L2-normalize tokens rows -> tn (bf16).  float4-vectorized, 32 lanes/token.
__global__ __launch_bounds__(256) void l2n_kernel(const float4* __restrict__ tokens4,
                                                  __bf16* __restrict__ tn) {
    int tid = threadIdx.x;
    int wave = tid >> 6, lane = tid & 63;
    int half = lane >> 5, l32 = lane & 31;
    long tok = (long)blockIdx.x * 8 + wave * 2 + half;
    float4 t = tokens4[tok * 32 + l32];
    float q = t.x * t.x + t.y * t.y + t.z * t.z + t.w * t.w;
    #pragma unroll
    for (int o = 16; o; o >>= 1) q += __shfl_xor(q, o);
    float inv = 1.0f / fmaxf(sqrtf(q), 1e-6f);
    bf16_4 o4;
    o4[0] = (__bf16)(t.x * inv); o4[1] = (__bf16)(t.y * inv);
    o4[2] = (__bf16)(t.z * inv); o4[3] = (__bf16)(t.w * inv);
    *(bf16_4*)(tn + tok * 128 + l32 * 4) = o4;
}

// ---------------------------------------------------------------------------
// MLP via MFMA: logits[m] = gelu(tn[m,:] @ W1.T + b1) @ W2 + b2
#define LDA 136   // 128 + 8 pad (bf16 elems), row stride 272 B
__global__ __launch_bounds__(256) void mlp_kernel(const __bf16* __restrict__ tn,
                                                  const __bf16* __restrict__ w1b,
                                                  const float* __restrict__ b1,
                                                  const float* __restrict__ W2,
                                                  const float* __restrict__ b2,
                                                  float* __restrict__ logits) {
    __shared__ __bf16 As[128 * LDA];   // 34816 B
    __shared__ __bf16 Bs[64 * LDA];    // 17408 B
    int tid = threadIdx.x;
    long m0 = (long)blockIdx.x * 128;
    const __bf16* asrc = tn + m0 * 128;
    #pragma unroll
    for (int i = 0; i < 8; ++i) {
        int idx = tid + i * 256;           // 0..2047
        int row = idx >> 4, c = idx & 15;  // 16 uint4 per row
        uint4 v = *(const uint4*)(asrc + row * 128 + c * 8);
        *(uint4*)(As + row * LDA + c * 8) = v;
    }
    #pragma unroll
    for (int i = 0; i < 4; ++i) {
        int idx = tid + i * 256;
        int row = idx >> 4, c = idx & 15;
        uint4 v = *(const uint4*)(w1b + row * 128 + c * 8);
        *(uint4*)(Bs + row * LDA + c * 8) = v;
    }
    __syncthreads();

    int wave = tid >> 6, lane = tid & 63;
    int lrow = lane & 15, lk = (lane >> 4) * 8;
    f32_4 acc[2][4] = {};
    #pragma unroll
    for (int kk = 0; kk < 128; kk += 32) {
        bf16_8 a[2], b[4];
        #pragma unroll
        for (int mt = 0; mt < 2; ++mt)
            a[mt] = *(const bf16_8*)(As + (wave * 32 + mt * 16 + lrow) * LDA + kk + lk);
        #pragma unroll
        for (int nt = 0; nt < 4; ++nt)
            b[nt] = *(const bf16_8*)(Bs + (nt * 16 + lrow) * LDA + kk + lk);
        #pragma unroll
        for (int mt = 0; mt < 2; ++mt)
            #pragma unroll
            for (int nt = 0; nt < 4; ++nt)
                acc[mt][nt] = __builtin_amdgcn_mfma_f32_16x16x32_bf16(
                    a[mt], b[nt], acc[mt][nt], 0, 0, 0);
    }

    int col = lane & 15, quad = lane >> 4;
    float b2v = b2[0];
    #pragma unroll
    for (int mt = 0; mt < 2; ++mt) {
        #pragma unroll
        for (int r = 0; r < 4; ++r) {
            float p = 0.0f;
            #pragma unroll
            for (int nt = 0; nt < 4; ++nt) {
                int jx = nt * 16 + col;
                float a = acc[mt][nt][r] + b1[jx];
                float gl = 0.5f * a * (1.0f + erff(a * 0.70710678118654752f));
                p += gl * W2[jx];
            }
            #pragma unroll
            for (int o = 8; o; o >>= 1) p += __shfl_xor(p, o);
            if (col == 0) {
                long tok = m0 + wave * 32 + mt * 16 + quad * 4 + r;
                logits[tok] = p + b2v;
            }
        }
    }
}

// ---------------------------------------------------------------------------
// Per-batch softmax over L, feats = sum_l w_l * tokens, 3 small head linears
__global__ __launch_bounds__(256) void head_kernel(const float* __restrict__ tokens,
                                                   const float* __restrict__ logits,
                                                   const float* __restrict__ texW,
                                                   const float* __restrict__ texb,
                                                   const float* __restrict__ edgeW,
                                                   const float* __restrict__ edgeb,
                                                   const float* __restrict__ strW,
                                                   const float* __restrict__ strb,
                                                   float* __restrict__ feats_out,
                                                   float* __restrict__ tex_out,
                                                   float* __restrict__ edge_out,
                                                   float* __restrict__ str_out,
                                                   float* __restrict__ w_out) {
    __shared__ float wsm[256];
    __shared__ float red[8];
    __shared__ float feats_s[128];
    int b = blockIdx.x, tid = threadIdx.x;
    int lane = tid & 63, wave = tid >> 6;
    float lg = logits[(long)b * 256 + tid];
    float mx = lg;
    #pragma unroll
    for (int o = 32; o; o >>= 1) mx = fmaxf(mx, __shfl_xor(mx, o));
    if (lane == 0) red[wave] = mx;
    __syncthreads();
    float bm = fmaxf(fmaxf(red[0], red[1]), fmaxf(red[2], red[3]));
    float e = expf(lg - bm);
    float se = e;
    #pragma unroll
    for (int o = 32; o; o >>= 1) se += __shfl_xor(se, o);
    if (lane == 0) red[4 + wave] = se;
    __syncthreads();
    float tot = red[4] + red[5] + red[6] + red[7];
    float w = e / tot;
    wsm[tid] = w;
    w_out[(long)b * 256 + tid] = w;
    __syncthreads();
    if (tid < 128) {
        float acc = 0.0f;
        const float* tb = tokens + (long)b * 256 * 128 + tid;
        #pragma unroll 4
        for (int l = 0; l < 256; ++l) acc += tb[l * 128] * wsm[l];
        feats_s[tid] = acc;
        feats_out[(long)b * 128 + tid] = acc;
    }
    __syncthreads();
    if (tid < 192) {
        int head = tid >> 6, j = tid & 63;
        const float* W  = head == 0 ? texW : (head == 1 ? edgeW : strW);
        const float* bi = head == 0 ? texb : (head == 1 ? edgeb : strb);
        float* outp     = head == 0 ? tex_out : (head == 1 ? edge_out : str_out);
        const float* wr = W + j * 128;
        float acc = 0.0f;
        #pragma unroll 8
        for (int k = 0; k < 128; ++k) acc += feats_s[k] * wr[k];
        outp[(long)b * 64 + j] = acc + bi[j];
    }
}

// ---------------------------------------------------------------------------
extern "C" void kernel_launch(void* const* d_in, const int* in_sizes, int n_in,
                              void* d_out, int out_size, void* d_ws, size_t ws_size,
                              hipStream_t stream) {
    const float* init   = (const float*)d_in[0];
    const float* pos    = (const float*)d_in[1];
    const float* ln_g   = (const float*)d_in[2];
    const float* ln_b   = (const float*)d_in[3];
    const float* W_in   = (const float*)d_in[4];
    const float* conv_w = (const float*)d_in[5];
    const float* conv_b = (const float*)d_in[6];
    const float* ssm_B  = (const float*)d_in[7];
    const float* ssm_C  = (const float*)d_in[8];
    const float* log_dt = (const float*)d_in[9];
    const float* ssm_D  = (const float*)d_in[10];
    const float* W_out  = (const float*)d_in[11];
    const float* res_sc = (const float*)d_in[12];
    const float* fin_g  = (const float*)d_in[13];
    const float* fin_b  = (const float*)d_in[14];
    const float* imp_W1 = (const float*)d_in[15];
    const float* imp_b1 = (const float*)d_in[16];
    const float* imp_W2 = (const float*)d_in[17];
    const float* imp_b2 = (const float*)d_in[18];
    const float* tex_W  = (const float*)d_in[19];
    const float* tex_b  = (const float*)d_in[20];
    const float* edge_W = (const float*)d_in[21];
    const float* edge_b = (const float*)d_in[22];
    const float* str_W  = (const float*)d_in[23];
    const float* str_b  = (const float*)d_in[24];

    float* out = (float*)d_out;
    char* ws = (char*)d_ws;
    float*  x      = (float*)ws;                      // 67108864 B  (M*D fp32)
    __bf16* xpt    = (__bf16*)(ws + 67108864);        // 67108864 B  (xp transposed [b][c][l])
    __bf16* zb     = (__bf16*)(ws + 134217728);       // 67108864 B  (z; y in place)
    __bf16* hb     = (__bf16*)(ws + 201326592);       // 33554432 B  (M*D bf16; reused as tn)
    __bf16* win16  = (__bf16*)(ws + 234881024);       // 524288 B
    __bf16* wout16 = (__bf16*)(ws + 235405312);       // 262144 B
    float*  logits = (float*)(ws + 235667456);        // 524288 B
    __bf16* w1b    = (__bf16*)(ws + 236191744);       // 16384 B
    __bf16* Tg     = (__bf16*)(ws + 236208128);       // 524288 B (4 layers x 256x256 bf16)
    float*  Rg     = (float*)(ws + 236732416);        // 4096 B (4 layers x 256 row sums)

    float* tokens = out + 163840;

    prep_kernel<<<1024, 256, 0, stream>>>(W_in, W_out, imp_W1, win16, wout16, w1b);
    build_T_kernel<<<dim3(256, 4), 256, 0, stream>>>(ssm_B, ssm_C, log_dt, ssm_D, Tg, Rg);
    ln_first_kernel<<<16384, 256, 0, stream>>>((const float4*)init, (const float4*)pos,
                                               ln_g, ln_b, (float4*)x, hb);
    for (int l = 0; l < 4; ++l) {
        gemm1_kernel<<<4096, 256, 0, stream>>>(hb, win16 + l * 65536, xpt, zb);
        ssm_gemm_kernel<<<1024, 512, 0, stream>>>(xpt, zb, Tg + l * 65536, Rg + l * 256,
                                                  conv_w + l * 1024, conv_b + l * 256);
        int fin = (l == 3);
        const float* gn = fin ? fin_g : ln_g + (l + 1) * 128;
        const float* bn = fin ? fin_b : ln_b + (l + 1) * 128;
        gemm2_kernel<<<2048, 256, 0, stream>>>(zb, wout16 + l * 32768, x, res_sc + l,
                                               gn, bn, hb, fin ? tokens : nullptr, fin);
    }
    __bf16* tn = hb;  // hb is dead after the layer loop; l2n writes tn here
    l2n_kernel<<<16384, 256, 0, stream>>>((const float4*)tokens, tn);
    mlp_kernel<<<1024, 256, 0, stream>>>(tn, w1b, imp_b1, imp_W2, imp_b2, logits);
    head_kernel<<<512, 256, 0, stream>>>(tokens, logits, tex_W, tex_b, edge_W, edge_b,
                                         str_W, str_b, out, out + 65536, out + 98304,
                                         out + 131072, out + 16941056);
}

// Round 9
// 697.806 us; speedup vs baseline: 2.1573x; 1.0990x over previous
//
#include <hip/hip_runtime.h>
#include <hip/hip_bf16.h>

// Problem constants
// B=512, N(L)=256, D=128, DI=256, NL=4, NS=16, KC=4, DH=64, H=64
// M = B*N = 131072 tokens

typedef __bf16 bf16_8 __attribute__((ext_vector_type(8)));
typedef __bf16 bf16_4 __attribute__((ext_vector_type(4)));
typedef float  f32_4  __attribute__((ext_vector_type(4)));

// global_load_lds width-16: linear LDS dest (wave base + lane*16), per-lane
// pre-swizzled global source; reads apply the same XOR (both-sides swizzle).
#define GLOAD16(src, dst) __builtin_amdgcn_global_load_lds( \
    (const __attribute__((address_space(1))) void*)(src),   \
    (__attribute__((address_space(3))) void*)(dst), 16, 0, 0)

// fast sigmoid: native v_exp + v_rcp (bf16 output hides <=2ulp error)
__device__ __forceinline__ float fsig(float z) {
    float e = __expf(-z);
    return __builtin_amdgcn_rcpf(1.0f + e);
}

// ---------------------------------------------------------------------------
// prep: convert W_in (4*512*128), W_out (4*128*256), imp_W1 (64*128) fp32->bf16
__global__ __launch_bounds__(256) void prep_kernel(const float* __restrict__ win,
                                                   const float* __restrict__ wout,
                                                   const float* __restrict__ w1,
                                                   __bf16* __restrict__ win16,
                                                   __bf16* __restrict__ wout16,
                                                   __bf16* __restrict__ w116) {
    int i = blockIdx.x * 256 + threadIdx.x;
    if (i < 4 * 512 * 128) win16[i] = (__bf16)win[i];
    if (i < 4 * 128 * 256) wout16[i] = (__bf16)wout[i];
    if (i < 64 * 128)      w116[i]  = (__bf16)w1[i];
}

// ---------------------------------------------------------------------------
// build_T: T[layer][l][j] = Kk[l-j] + (l==j)*Dp, 0 for j>l  (bf16, 256x256/layer)
// Also emits row sums Rg[layer][l] = sum_j T[l,j] (of the bf16-rounded values).
__global__ __launch_bounds__(256) void build_T_kernel(const float* __restrict__ Bp,
                                                      const float* __restrict__ Cp,
                                                      const float* __restrict__ ldt,
                                                      const float* __restrict__ Dpv,
                                                      __bf16* __restrict__ Tg,
                                                      float* __restrict__ Rg) {
    __shared__ float rsum[4];
    int layer = blockIdx.y, l = blockIdx.x, j = threadIdx.x;
    int d = l - j;
    float val = 0.0f;
    if (d >= 0) {
        float dt = expf(ldt[layer]);
        dt = fminf(fmaxf(dt, 1e-4f), 1.0f);
        #pragma unroll
        for (int n = 0; n < 16; ++n) {
            float A = -(float)(n + 1);
            float e = fminf(fmaxf(dt * A, -10.0f), 10.0f);
            float dA = expf(e);
            float dB = (dA - 1.0f) / A * Bp[layer * 16 + n];
            val += Cp[layer * 16 + n] * dB * expf(e * (float)d);
        }
        if (d == 0) val += Dpv[layer];
    }
    __bf16 bv = (__bf16)val;
    Tg[layer * 65536 + l * 256 + j] = bv;
    float fv = (float)bv;
    #pragma unroll
    for (int o = 32; o; o >>= 1) fv += __shfl_xor(fv, o);
    int lane = j & 63, wave = j >> 6;
    if (lane == 0) rsum[wave] = fv;
    __syncthreads();
    if (j == 0) Rg[layer * 256 + l] = rsum[0] + rsum[1] + rsum[2] + rsum[3];
}

// ---------------------------------------------------------------------------
// Fused add_pos + first LayerNorm, float4-vectorized: 32 lanes per token.
// x = init+pos (bf16 residual stream), h = LN(x) bf16.
__global__ __launch_bounds__(256) void ln_first_kernel(const float4* __restrict__ init4,
                                                       const float4* __restrict__ pos4,
                                                       const float* __restrict__ g,
                                                       const float* __restrict__ bta,
                                                       __bf16* __restrict__ x,
                                                       __bf16* __restrict__ h) {
    int tid = threadIdx.x;
    int wave = tid >> 6, lane = tid & 63;
    int half = lane >> 5, l32 = lane & 31;
    long tok = (long)blockIdx.x * 8 + wave * 2 + half;
    float4 v = init4[tok * 32 + l32];
    float4 p = pos4[(tok & 255) * 32 + l32];
    v.x += p.x; v.y += p.y; v.z += p.z; v.w += p.w;
    int d0 = l32 * 4;
    bf16_4 xv;
    xv[0] = (__bf16)v.x; xv[1] = (__bf16)v.y; xv[2] = (__bf16)v.z; xv[3] = (__bf16)v.w;
    *(bf16_4*)(x + tok * 128 + d0) = xv;
    float s = v.x + v.y + v.z + v.w;
    float ss = v.x * v.x + v.y * v.y + v.z * v.z + v.w * v.w;
    #pragma unroll
    for (int o = 16; o; o >>= 1) { s += __shfl_xor(s, o); ss += __shfl_xor(ss, o); }
    float m = s * (1.0f / 128.0f);
    float var = ss * (1.0f / 128.0f) - m * m;
    float r = rsqrtf(var + 1e-5f);
    bf16_4 hv;
    hv[0] = (__bf16)((v.x - m) * r * g[d0]     + bta[d0]);
    hv[1] = (__bf16)((v.y - m) * r * g[d0 + 1] + bta[d0 + 1]);
    hv[2] = (__bf16)((v.z - m) * r * g[d0 + 2] + bta[d0 + 2]);
    hv[3] = (__bf16)((v.w - m) * r * g[d0 + 3] + bta[d0 + 3]);
    *(bf16_4*)(h + tok * 128 + d0) = hv;
}

// ---------------------------------------------------------------------------
// GEMM1: xz[m,n] = sum_k h[m,k] * Win[n,k]; M=131072, N=512, K=128.
// Staging via global_load_lds (linear LDS, source-XOR swizzle).
// 1D grid 4096, XCD-aware fold: the 4 n-tiles of one m-tile share bid%8
// (same XCD) and dispatch within a 32-bid window -> h tile is L2-hit 3 of 4x
// (verified: FETCH 132->17 MB).
// xp written TRANSPOSED (RAW, pre-conv): xpt[b][n][l]; z written in [m][c].
__global__ __launch_bounds__(256) void gemm1_kernel(const __bf16* __restrict__ hmat,
                                                    const __bf16* __restrict__ win,
                                                    __bf16* __restrict__ xpt,
                                                    __bf16* __restrict__ z) {
    __shared__ __align__(16) __bf16 As[128 * 64];   // 16 KB
    __shared__ __align__(16) __bf16 Bs[128 * 64];   // 16 KB
    int tid = threadIdx.x;
    int bid = blockIdx.x;
    // decode: m = (bid&7) + 8*(bid>>5), n = (bid>>3)&3  (bijective, 4096 blocks)
    long m0 = (long)((bid & 7) + ((bid >> 5) << 3)) * 128;
    int n0 = ((bid >> 3) & 3) * 128;
    int wave = tid >> 6, lane = tid & 63;
    int wm = wave >> 1, wn = wave & 1;
    int lrow = lane & 15, lk = (lane >> 4) * 8;
    int r7 = lrow & 7;
    int rl = lane >> 3, sl = lane & 7;
    int scol = ((sl ^ rl) << 3);                    // source-swizzled 16B chunk
    f32_4 acc[4][4] = {};

    for (int kc = 0; kc < 2; ++kc) {
        const __bf16* asrc = hmat + m0 * 128 + kc * 64;
        const __bf16* bsrc = win + (long)n0 * 128 + kc * 64;
        #pragma unroll
        for (int j = 0; j < 4; ++j) {               // A: 16 chunks of 8 rows
            int chunk = wave * 4 + j;
            GLOAD16(asrc + (long)(chunk * 8 + rl) * 128 + scol, As + chunk * 512);
            GLOAD16(bsrc + (long)(chunk * 8 + rl) * 128 + scol, Bs + chunk * 512);
        }
        __syncthreads();
        #pragma unroll
        for (int kk = 0; kk < 64; kk += 32) {
            int sw = ((((kk + lk) >> 3) ^ r7) << 3);
            bf16_8 a[4], b[4];
            #pragma unroll
            for (int mt = 0; mt < 4; ++mt)
                a[mt] = *(const bf16_8*)(As + (wm * 64 + mt * 16 + lrow) * 64 + sw);
            #pragma unroll
            for (int nt = 0; nt < 4; ++nt)
                b[nt] = *(const bf16_8*)(Bs + (wn * 64 + nt * 16 + lrow) * 64 + sw);
            #pragma unroll
            for (int mt = 0; mt < 4; ++mt)
                #pragma unroll
                for (int nt = 0; nt < 4; ++nt)
                    acc[mt][nt] = __builtin_amdgcn_mfma_f32_16x16x32_bf16(
                        a[mt], b[nt], acc[mt][nt], 0, 0, 0);
        }
        __syncthreads();
    }

    int row_base = (lane >> 4) * 4;
    int col = lane & 15;
    if (n0 < 256) {
        // xp branch: transposed packed write xpt[b][n][l..l+3]
        #pragma unroll
        for (int mt = 0; mt < 4; ++mt) {
            long mg = m0 + wm * 64 + mt * 16 + row_base;
            int b = (int)(mg >> 8), l = (int)(mg & 255);  // l multiple of 4 -> 8B aligned
            #pragma unroll
            for (int nt = 0; nt < 4; ++nt) {
                int ng = n0 + wn * 64 + nt * 16 + col;
                bf16_4 o;
                #pragma unroll
                for (int r = 0; r < 4; ++r) o[r] = (__bf16)acc[mt][nt][r];
                *(bf16_4*)(xpt + (long)b * 65536 + (long)ng * 256 + l) = o;
            }
        }
    } else {
        int ncol0 = n0 - 256;
        #pragma unroll
        for (int mt = 0; mt < 4; ++mt) {
            long mg = m0 + wm * 64 + mt * 16 + row_base;
            #pragma unroll
            for (int nt = 0; nt < 4; ++nt) {
                int ng = ncol0 + wn * 64 + nt * 16 + col;
                #pragma unroll
                for (int r = 0; r < 4; ++r)
                    z[(mg + r) * 256 + ng] = (__bf16)acc[mt][nt][r];
            }
        }
    }
}

// ---------------------------------------------------------------------------
// SSM: P = T @ xp (per-batch Toeplitz GEMM, global_load_lds staging), conv(K=4)
// applied to P in the EPILOGUE via shifted-P identity; y *= sigmoid(z) in place.
// One block per (batch, channel-half): BM=256, BN=128, 512 threads.
// NOTE: plain launch_bounds(512) — (512,6) starved VGPRs (40, acc spilled to
// scratch: WRITE_SIZE 66->462MB, dur 63->236us).  Round-7 lesson.
__global__ __launch_bounds__(512) void ssm_gemm_kernel(const __bf16* __restrict__ xct,
                                                       __bf16* __restrict__ zy,
                                                       const __bf16* __restrict__ Tg,
                                                       const float* __restrict__ Rg,
                                                       const float* __restrict__ cw,
                                                       const float* __restrict__ cb) {
    __shared__ __align__(16) __bf16 As[256 * 64];   // 32 KB (T rows, K-chunk)
    __shared__ __align__(16) __bf16 Bs[128 * 64];   // 16 KB (x channels, K-chunk)
    __shared__ float  bnd[3][128];      // P rows 125..127 for wm=0 -> wm=1 handoff
    __shared__ float  Rs[256];
    int tid = threadIdx.x;
    int batch = blockIdx.x >> 1;
    int ntile = blockIdx.x & 1;
    int c0 = ntile * 128;

    int wave = tid >> 6, lane = tid & 63;
    int wm = wave >> 2, wn = wave & 3;          // 2 x 4 wave grid
    int lrow = lane & 15, lk = (lane >> 4) * 8;
    int r7 = lrow & 7;
    int quad = lane >> 4;
    int rl = lane >> 3, sl = lane & 7;
    int scol = ((sl ^ rl) << 3);
    f32_4 acc[8][2] = {};
    const __bf16* bsrc0 = xct + (long)batch * 65536 + (long)c0 * 256;

    if (tid < 256) Rs[tid] = Rg[tid];

    for (int kc = 0; kc < 4; ++kc) {
        int j0 = kc * 64;
        const __bf16* asrc = Tg + j0;
        const __bf16* bsrc = bsrc0 + j0;
        #pragma unroll
        for (int j = 0; j < 4; ++j) {           // A: 32 chunks / 8 waves
            int chunk = wave * 4 + j;
            GLOAD16(asrc + (long)(chunk * 8 + rl) * 256 + scol, As + chunk * 512);
        }
        #pragma unroll
        for (int j = 0; j < 2; ++j) {           // B: 16 chunks / 8 waves
            int chunk = wave * 2 + j;
            GLOAD16(bsrc + (long)(chunk * 8 + rl) * 256 + scol, Bs + chunk * 512);
        }
        __syncthreads();
        #pragma unroll
        for (int kk = 0; kk < 64; kk += 32) {
            int sw = ((((kk + lk) >> 3) ^ r7) << 3);
            bf16_8 b0 = *(const bf16_8*)(Bs + (wn * 32 + lrow) * 64 + sw);
            bf16_8 b1 = *(const bf16_8*)(Bs + (wn * 32 + 16 + lrow) * 64 + sw);
            #pragma unroll
            for (int mt = 0; mt < 8; ++mt) {
                bf16_8 a = *(const bf16_8*)(As + (wm * 128 + mt * 16 + lrow) * 64 + sw);
                acc[mt][0] = __builtin_amdgcn_mfma_f32_16x16x32_bf16(a, b0, acc[mt][0], 0, 0, 0);
                acc[mt][1] = __builtin_amdgcn_mfma_f32_16x16x32_bf16(a, b1, acc[mt][1], 0, 0, 0);
            }
        }
        __syncthreads();
    }

    // publish P rows 125..127 (wm=0, top tile, quad 3, r=1..3) for wm=1 waves
    if (wm == 0 && quad == 3) {
        #pragma unroll
        for (int nt = 0; nt < 2; ++nt) {
            int colb = wn * 32 + nt * 16 + lrow;
            bnd[0][colb] = acc[7][nt][1];   // P[125]
            bnd[1][colb] = acc[7][nt][2];   // P[126]
            bnd[2][colb] = acc[7][nt][3];   // P[127]
        }
    }
    __syncthreads();

    // per-channel conv weights
    float4 wv[2]; float cbv[2];
    #pragma unroll
    for (int nt = 0; nt < 2; ++nt) {
        int cg = c0 + wn * 32 + nt * 16 + lrow;
        wv[nt] = *(const float4*)(cw + cg * 4);
        cbv[nt] = cb[cg];
    }
    int src = (lane + 48) & 63;   // quad>0: lane-16 ; quad==0: lane+48

    #pragma unroll
    for (int mt = 0; mt < 8; ++mt) {
        int lbase = wm * 128 + mt * 16 + quad * 4;
        int mp = mt > 0 ? mt - 1 : 0;
        float R0 = Rs[lbase], R1 = Rs[lbase + 1], R2 = Rs[lbase + 2], R3 = Rs[lbase + 3];
        #pragma unroll
        for (int nt = 0; nt < 2; ++nt) {
            int colb = wn * 32 + nt * 16 + lrow;
            int cg = c0 + colb;
            // P at rows lbase-1, lbase-2, lbase-3
            float s1 = __shfl(acc[mt][nt][3], src);
            float s2 = __shfl(acc[mt][nt][2], src);
            float s3 = __shfl(acc[mt][nt][1], src);
            float t1, t2, t3;
            if (mt == 0) {
                if (wm == 1) { t1 = bnd[2][colb]; t2 = bnd[1][colb]; t3 = bnd[0][colb]; }
                else         { t1 = 0.0f; t2 = 0.0f; t3 = 0.0f; }
            } else {
                t1 = __shfl(acc[mp][nt][3], src);
                t2 = __shfl(acc[mp][nt][2], src);
                t3 = __shfl(acc[mp][nt][1], src);
            }
            float pm1 = quad ? s1 : t1;
            float pm2 = quad ? s2 : t2;
            float pm3 = quad ? s3 : t3;
            float p0 = acc[mt][nt][0], p1 = acc[mt][nt][1];
            float p2 = acc[mt][nt][2], p3 = acc[mt][nt][3];
            float y0 = wv[nt].x * pm3 + wv[nt].y * pm2 + wv[nt].z * pm1 + wv[nt].w * p0 + cbv[nt] * R0;
            float y1 = wv[nt].x * pm2 + wv[nt].y * pm1 + wv[nt].z * p0  + wv[nt].w * p1 + cbv[nt] * R1;
            float y2 = wv[nt].x * pm1 + wv[nt].y * p0  + wv[nt].z * p1  + wv[nt].w * p2 + cbv[nt] * R2;
            float y3 = wv[nt].x * p0  + wv[nt].y * p1  + wv[nt].z * p2  + wv[nt].w * p3 + cbv[nt] * R3;
            long base = (long)batch * 65536 + (long)lbase * 256 + cg;
            float z0 = (float)zy[base];
            float z1 = (float)zy[base + 256];
            float z2 = (float)zy[base + 512];
            float z3 = (float)zy[base + 768];
            zy[base]       = (__bf16)(y0 * fsig(z0));
            zy[base + 256] = (__bf16)(y1 * fsig(z1));
            zy[base + 512] = (__bf16)(y2 * fsig(z2));
            zy[base + 768] = (__bf16)(y3 * fsig(z3));
        }
    }
}

// ---------------------------------------------------------------------------
// GEMM2 + residual + FUSED LayerNorm epilogue (global_load_lds staging).
//   xn[m,d] = x[m,d] + clip(rs)*sum_c y[m,c]*Wout[d,c]   (M=131072,N=128,K=256)
// Residual stream x is bf16 (compute in fp32).  M-tile 64 (grid 2048).
// final_mode==0: x updated (bf16) + LN(xn) bf16 -> hout.
// final_mode==1: LN(xn) fp32 -> tokens_out; x NOT written (dead afterwards).
__global__ __launch_bounds__(256) void gemm2_kernel(const __bf16* __restrict__ y,
                                                    const __bf16* __restrict__ wout,
                                                    __bf16* __restrict__ x,
                                                    const float* __restrict__ rs_p,
                                                    const float* __restrict__ g,
                                                    const float* __restrict__ bta,
                                                    __bf16* __restrict__ hout,
                                                    float* __restrict__ tokens_out,
                                                    int final_mode) {
    __shared__ __align__(16) __bf16 As[64 * 64];    // 8 KB
    __shared__ __align__(16) __bf16 Bs[128 * 64];   // 16 KB
    __shared__ float s_sum[64][2];
    __shared__ float s_ssq[64][2];
    int tid = threadIdx.x;
    long m0 = (long)blockIdx.x * 64;
    int wave = tid >> 6, lane = tid & 63;
    int wm = wave >> 1, wn = wave & 1;
    int lrow = lane & 15, lk = (lane >> 4) * 8;
    int r7 = lrow & 7;
    int rl = lane >> 3, sl = lane & 7;
    int scol = ((sl ^ rl) << 3);
    f32_4 acc[2][4] = {};

    for (int kc = 0; kc < 4; ++kc) {
        const __bf16* asrc = y + m0 * 256 + kc * 64;
        const __bf16* bsrc = wout + kc * 64;
        #pragma unroll
        for (int j = 0; j < 2; ++j) {               // A: 8 chunk-groups / 4 waves
            int chunk = wave * 2 + j;
            GLOAD16(asrc + (long)(chunk * 8 + rl) * 256 + scol, As + chunk * 512);
        }
        #pragma unroll
        for (int j = 0; j < 4; ++j) {               // B: 16 chunk-groups / 4 waves
            int chunk = wave * 4 + j;
            GLOAD16(bsrc + (long)(chunk * 8 + rl) * 256 + scol, Bs + chunk * 512);
        }
        __syncthreads();
        #pragma unroll
        for (int kk = 0; kk < 64; kk += 32) {
            int sw = ((((kk + lk) >> 3) ^ r7) << 3);
            bf16_8 a[2], b[4];
            #pragma unroll
            for (int mt = 0; mt < 2; ++mt)
                a[mt] = *(const bf16_8*)(As + (wm * 32 + mt * 16 + lrow) * 64 + sw);
            #pragma unroll
            for (int nt = 0; nt < 4; ++nt)
                b[nt] = *(const bf16_8*)(Bs + (wn * 64 + nt * 16 + lrow) * 64 + sw);
            #pragma unroll
            for (int mt = 0; mt < 2; ++mt)
                #pragma unroll
                for (int nt = 0; nt < 4; ++nt)
                    acc[mt][nt] = __builtin_amdgcn_mfma_f32_16x16x32_bf16(
                        a[mt], b[nt], acc[mt][nt], 0, 0, 0);
        }
        __syncthreads();
    }

    float rs = rs_p[0];
    rs = fminf(fmaxf(rs, 0.0f), 1.5f);
    int quad = lane >> 4;
    int col = lane & 15;

    // Phase A: xn = x + rs*acc (overwrite acc); per-token partial sum/sumsq
    #pragma unroll
    for (int mt = 0; mt < 2; ++mt) {
        int tb = wm * 32 + mt * 16 + quad * 4;
        long mg = m0 + tb;
        #pragma unroll
        for (int r = 0; r < 4; ++r) {
            float s = 0.0f, ss = 0.0f;
            #pragma unroll
            for (int nt = 0; nt < 4; ++nt) {
                int d = wn * 64 + nt * 16 + col;
                float xv = (float)x[(mg + r) * 128 + d] + rs * acc[mt][nt][r];
                acc[mt][nt][r] = xv;
                s += xv; ss += xv * xv;
            }
            #pragma unroll
            for (int o = 8; o; o >>= 1) { s += __shfl_xor(s, o); ss += __shfl_xor(ss, o); }
            if (col == 0) {
                s_sum[tb + r][wn] = s;
                s_ssq[tb + r][wn] = ss;
            }
        }
    }
    __syncthreads();

    // Phase B: finish LN, write outputs
    #pragma unroll
    for (int mt = 0; mt < 2; ++mt) {
        int tb = wm * 32 + mt * 16 + quad * 4;
        long mg = m0 + tb;
        #pragma unroll
        for (int r = 0; r < 4; ++r) {
            float s  = s_sum[tb + r][0] + s_sum[tb + r][1];
            float ss = s_ssq[tb + r][0] + s_ssq[tb + r][1];
            float m = s * (1.0f / 128.0f);
            float var = ss * (1.0f / 128.0f) - m * m;
            float rstd = rsqrtf(var + 1e-5f);
            #pragma unroll
            for (int nt = 0; nt < 4; ++nt) {
                int d = wn * 64 + nt * 16 + col;
                float xv = acc[mt][nt][r];
                float t = (xv - m) * rstd * g[d] + bta[d];
                if (!final_mode) {
                    x[(mg + r) * 128 + d] = (__bf16)xv;
                    hout[(mg + r) * 128 + d] = (__bf16)t;
                } else {
                    tokens_out[(mg + r) * 128 + d] = t;
                }
            }
        }
    }
}

// ---------------------------------------------------------------------------
// L2-normalize tokens rows -> tn (bf16).  float4-vectorized, 32 lanes/token.
__global__ __launch_bounds__(256) void l2n_kernel(const float4* __restrict__ tokens4,
                                                  __bf16* __restrict__ tn) {
    int tid = threadIdx.x;
    int wave = tid >> 6, lane = tid & 63;
    int half = lane >> 5, l32 = lane & 31;
    long tok = (long)blockIdx.x * 8 + wave * 2 + half;
    float4 t = tokens4[tok * 32 + l32];
    float q = t.x * t.x + t.y * t.y + t.z * t.z + t.w * t.w;
    #pragma unroll
    for (int o = 16; o; o >>= 1) q += __shfl_xor(q, o);
    float inv = 1.0f / fmaxf(sqrtf(q), 1e-6f);
    bf16_4 o4;
    o4[0] = (__bf16)(t.x * inv); o4[1] = (__bf16)(t.y * inv);
    o4[2] = (__bf16)(t.z * inv); o4[3] = (__bf16)(t.w * inv);
    *(bf16_4*)(tn + tok * 128 + l32 * 4) = o4;
}

// ---------------------------------------------------------------------------
// MLP via MFMA: logits[m] = gelu(tn[m,:] @ W1.T + b1) @ W2 + b2
#define LDA 136   // 128 + 8 pad (bf16 elems), row stride 272 B
__global__ __launch_bounds__(256) void mlp_kernel(const __bf16* __restrict__ tn,
                                                  const __bf16* __restrict__ w1b,
                                                  const float* __restrict__ b1,
                                                  const float* __restrict__ W2,
                                                  const float* __restrict__ b2,
                                                  float* __restrict__ logits) {
    __shared__ __bf16 As[128 * LDA];   // 34816 B
    __shared__ __bf16 Bs[64 * LDA];    // 17408 B
    int tid = threadIdx.x;
    long m0 = (long)blockIdx.x * 128;
    const __bf16* asrc = tn + m0 * 128;
    #pragma unroll
    for (int i = 0; i < 8; ++i) {
        int idx = tid + i * 256;           // 0..2047
        int row = idx >> 4, c = idx & 15;  // 16 uint4 per row
        uint4 v = *(const uint4*)(asrc + row * 128 + c * 8);
        *(uint4*)(As + row * LDA + c * 8) = v;
    }
    #pragma unroll
    for (int i = 0; i < 4; ++i) {
        int idx = tid + i * 256;
        int row = idx >> 4, c = idx & 15;
        uint4 v = *(const uint4*)(w1b + row * 128 + c * 8);
        *(uint4*)(Bs + row * LDA + c * 8) = v;
    }
    __syncthreads();

    int wave = tid >> 6, lane = tid & 63;
    int lrow = lane & 15, lk = (lane >> 4) * 8;
    f32_4 acc[2][4] = {};
    #pragma unroll
    for (int kk = 0; kk < 128; kk += 32) {
        bf16_8 a[2], b[4];
        #pragma unroll
        for (int mt = 0; mt < 2; ++mt)
            a[mt] = *(const bf16_8*)(As + (wave * 32 + mt * 16 + lrow) * LDA + kk + lk);
        #pragma unroll
        for (int nt = 0; nt < 4; ++nt)
            b[nt] = *(const bf16_8*)(Bs + (nt * 16 + lrow) * LDA + kk + lk);
        #pragma unroll
        for (int mt = 0; mt < 2; ++mt)
            #pragma unroll
            for (int nt = 0; nt < 4; ++nt)
                acc[mt][nt] = __builtin_amdgcn_mfma_f32_16x16x32_bf16(
                    a[mt], b[nt], acc[mt][nt], 0, 0, 0);
    }

    int col = lane & 15, quad = lane >> 4;
    float b2v = b2[0];
    #pragma unroll
    for (int mt = 0; mt < 2; ++mt) {
        #pragma unroll
        for (int r = 0; r < 4; ++r) {
            float p = 0.0f;
            #pragma unroll
            for (int nt = 0; nt < 4; ++nt) {
                int jx = nt * 16 + col;
                float a = acc[mt][nt][r] + b1[jx];
                float gl = 0.5f * a * (1.0f + erff(a * 0.70710678118654752f));
                p += gl * W2[jx];
            }
            #pragma unroll
            for (int o = 8; o; o >>= 1) p += __shfl_xor(p, o);
            if (col == 0) {
                long tok = m0 + wave * 32 + mt * 16 + quad * 4 + r;
                logits[tok] = p + b2v;
            }
        }
    }
}

// ---------------------------------------------------------------------------
// Per-batch softmax over L, feats = sum_l w_l * tokens, 3 small head linears
__global__ __launch_bounds__(256) void head_kernel(const float* __restrict__ tokens,
                                                   const float* __restrict__ logits,
                                                   const float* __restrict__ texW,
                                                   const float* __restrict__ texb,
                                                   const float* __restrict__ edgeW,
                                                   const float* __restrict__ edgeb,
                                                   const float* __restrict__ strW,
                                                   const float* __restrict__ strb,
                                                   float* __restrict__ feats_out,
                                                   float* __restrict__ tex_out,
                                                   float* __restrict__ edge_out,
                                                   float* __restrict__ str_out,
                                                   float* __restrict__ w_out) {
    __shared__ float wsm[256];
    __shared__ float red[8];
    __shared__ float feats_s[128];
    int b = blockIdx.x, tid = threadIdx.x;
    int lane = tid & 63, wave = tid >> 6;
    float lg = logits[(long)b * 256 + tid];
    float mx = lg;
    #pragma unroll
    for (int o = 32; o; o >>= 1) mx = fmaxf(mx, __shfl_xor(mx, o));
    if (lane == 0) red[wave] = mx;
    __syncthreads();
    float bm = fmaxf(fmaxf(red[0], red[1]), fmaxf(red[2], red[3]));
    float e = expf(lg - bm);
    float se = e;
    #pragma unroll
    for (int o = 32; o; o >>= 1) se += __shfl_xor(se, o);
    if (lane == 0) red[4 + wave] = se;
    __syncthreads();
    float tot = red[4] + red[5] + red[6] + red[7];
    float w = e / tot;
    wsm[tid] = w;
    w_out[(long)b * 256 + tid] = w;
    __syncthreads();
    if (tid < 128) {
        float acc = 0.0f;
        const float* tb = tokens + (long)b * 256 * 128 + tid;
        #pragma unroll 4
        for (int l = 0; l < 256; ++l) acc += tb[l * 128] * wsm[l];
        feats_s[tid] = acc;
        feats_out[(long)b * 128 + tid] = acc;
    }
    __syncthreads();
    if (tid < 192) {
        int head = tid >> 6, j = tid & 63;
        const float* W  = head == 0 ? texW : (head == 1 ? edgeW : strW);
        const float* bi = head == 0 ? texb : (head == 1 ? edgeb : strb);
        float* outp     = head == 0 ? tex_out : (head == 1 ? edge_out : str_out);
        const float* wr = W + j * 128;
        float acc = 0.0f;
        #pragma unroll 8
        for (int k = 0; k < 128; ++k) acc += feats_s[k] * wr[k];
        outp[(long)b * 64 + j] = acc + bi[j];
    }
}

// ---------------------------------------------------------------------------
extern "C" void kernel_launch(void* const* d_in, const int* in_sizes, int n_in,
                              void* d_out, int out_size, void* d_ws, size_t ws_size,
                              hipStream_t stream) {
    const float* init   = (const float*)d_in[0];
    const float* pos    = (const float*)d_in[1];
    const float* ln_g   = (const float*)d_in[2];
    const float* ln_b   = (const float*)d_in[3];
    const float* W_in   = (const float*)d_in[4];
    const float* conv_w = (const float*)d_in[5];
    const float* conv_b = (const float*)d_in[6];
    const float* ssm_B  = (const float*)d_in[7];
    const float* ssm_C  = (const float*)d_in[8];
    const float* log_dt = (const float*)d_in[9];
    const float* ssm_D  = (const float*)d_in[10];
    const float* W_out  = (const float*)d_in[11];
    const float* res_sc = (const float*)d_in[12];
    const float* fin_g  = (const float*)d_in[13];
    const float* fin_b  = (const float*)d_in[14];
    const float* imp_W1 = (const float*)d_in[15];
    const float* imp_b1 = (const float*)d_in[16];
    const float* imp_W2 = (const float*)d_in[17];
    const float* imp_b2 = (const float*)d_in[18];
    const float* tex_W  = (const float*)d_in[19];
    const float* tex_b  = (const float*)d_in[20];
    const float* edge_W = (const float*)d_in[21];
    const float* edge_b = (const float*)d_in[22];
    const float* str_W  = (const float*)d_in[23];
    const float* str_b  = (const float*)d_in[24];

    float* out = (float*)d_out;
    char* ws = (char*)d_ws;
    __bf16* x      = (__bf16*)ws;                     // 33554432 B  (M*D bf16 residual)
    __bf16* xpt    = (__bf16*)(ws + 67108864);        // 67108864 B  (xp transposed [b][c][l])
    __bf16* zb     = (__bf16*)(ws + 134217728);       // 67108864 B  (z; y in place)
    __bf16* hb     = (__bf16*)(ws + 201326592);       // 33554432 B  (M*D bf16; reused as tn)
    __bf16* win16  = (__bf16*)(ws + 234881024);       // 524288 B
    __bf16* wout16 = (__bf16*)(ws + 235405312);       // 262144 B
    float*  logits = (float*)(ws + 235667456);        // 524288 B
    __bf16* w1b    = (__bf16*)(ws + 236191744);       // 16384 B
    __bf16* Tg     = (__bf16*)(ws + 236208128);       // 524288 B (4 layers x 256x256 bf16)
    float*  Rg     = (float*)(ws + 236732416);        // 4096 B (4 layers x 256 row sums)

    float* tokens = out + 163840;

    prep_kernel<<<1024, 256, 0, stream>>>(W_in, W_out, imp_W1, win16, wout16, w1b);
    build_T_kernel<<<dim3(256, 4), 256, 0, stream>>>(ssm_B, ssm_C, log_dt, ssm_D, Tg, Rg);
    ln_first_kernel<<<16384, 256, 0, stream>>>((const float4*)init, (const float4*)pos,
                                               ln_g, ln_b, x, hb);
    for (int l = 0; l < 4; ++l) {
        gemm1_kernel<<<4096, 256, 0, stream>>>(hb, win16 + l * 65536, xpt, zb);
        ssm_gemm_kernel<<<1024, 512, 0, stream>>>(xpt, zb, Tg + l * 65536, Rg + l * 256,
                                                  conv_w + l * 1024, conv_b + l * 256);
        int fin = (l == 3);
        const float* gn = fin ? fin_g : ln_g + (l + 1) * 128;
        const float* bn = fin ? fin_b : ln_b + (l + 1) * 128;
        gemm2_kernel<<<2048, 256, 0, stream>>>(zb, wout16 + l * 32768, x, res_sc + l,
                                               gn, bn, hb, fin ? tokens : nullptr, fin);
    }
    __bf16* tn = hb;  // hb is dead after the layer loop; l2n writes tn here
    l2n_kernel<<<16384, 256, 0, stream>>>((const float4*)tokens, tn);
    mlp_kernel<<<1024, 256, 0, stream>>>(tn, w1b, imp_b1, imp_W2, imp_b2, logits);
    head_kernel<<<512, 256, 0, stream>>>(tokens, logits, tex_W, tex_b, edge_W, edge_b,
                                         str_W, str_b, out, out + 65536, out + 98304,
                                         out + 131072, out + 16941056);
}